// Round 1
// baseline (1186.035 us; speedup 1.0000x reference)
//
#include <hip/hip_runtime.h>

#define NN 50000
#define EE 640000
#define DINv 64
#define GBv 128
#define GDv 4
#define LBv 256
#define LDv 2
#define GGv 1024

// ---------------- degree / CSR build ----------------

__global__ void k_hist(const int* __restrict__ dst, int* __restrict__ cnt) {
  int i = blockIdx.x * blockDim.x + threadIdx.x;
  int stride = gridDim.x * blockDim.x;
  for (; i < EE; i += stride) atomicAdd(&cnt[dst[i]], 1);
}

__global__ void k_dinv(const int* __restrict__ cnt, float* __restrict__ dinv) {
  int i = blockIdx.x * blockDim.x + threadIdx.x;
  if (i < NN) dinv[i] = 1.0f / sqrtf((float)(cnt[i] + 1));
}

// single-block exclusive scan of cnt -> offs (offs[NN] = E)
__global__ void k_scan(const int* __restrict__ cnt, int* __restrict__ offs) {
  __shared__ int sh[256];
  __shared__ int base;
  int tid = threadIdx.x;
  if (tid == 0) base = 0;
  __syncthreads();
  for (int chunk = 0; chunk < NN; chunk += 256) {
    int idx = chunk + tid;
    int v = (idx < NN) ? cnt[idx] : 0;
    sh[tid] = v;
    __syncthreads();
    for (int off = 1; off < 256; off <<= 1) {
      int t = (tid >= off) ? sh[tid - off] : 0;
      __syncthreads();
      sh[tid] += t;
      __syncthreads();
    }
    if (idx < NN) offs[idx] = base + sh[tid] - v;
    __syncthreads();
    if (tid == 0) base += sh[255];
    __syncthreads();
  }
  if (tid == 0) offs[NN] = base;
}

__global__ void k_build(const int* __restrict__ ei, int* __restrict__ cursor,
                        int* __restrict__ col) {
  int i = blockIdx.x * blockDim.x + threadIdx.x;
  int stride = gridDim.x * blockDim.x;
  for (; i < EE; i += stride) {
    int d = ei[EE + i];
    int p = atomicAdd(&cursor[d], 1);
    col[p] = ei[i];
  }
}

// ---------------- dense matmul: hws[r][c] = (h @ W)[r][c] * dinv[r] ----------------
// h: [nrows x K], W: [K x 128], out 128 cols. Tile 64 rows x 128 cols per 256-thread block.

template <int K>
__global__ __launch_bounds__(256) void k_matmul(const float* __restrict__ h,
                                                const float* __restrict__ W,
                                                const float* __restrict__ dinv,
                                                float* __restrict__ hws, int nrows) {
  __shared__ float sA[64][36];
  __shared__ float sB[32][GBv];
  int tid = threadIdx.x;
  int tx = tid & 15;   // col group: cols tx*8 .. +8
  int ty = tid >> 4;   // row group: rows ty*4 .. +4
  int row0 = blockIdx.x * 64;
  float acc[4][8];
#pragma unroll
  for (int i = 0; i < 4; i++)
#pragma unroll
    for (int j = 0; j < 8; j++) acc[i][j] = 0.f;

  for (int k0 = 0; k0 < K; k0 += 32) {
    // A tile: 64x32, 8 consecutive floats per thread
    {
      int start = tid * 8;
      int r = start >> 5, kk = start & 31;
      int gr = row0 + r;
      float4 v0, v1;
      if (gr < nrows) {
        const float* p = &h[(long)gr * K + k0 + kk];
        v0 = *(const float4*)p;
        v1 = *(const float4*)(p + 4);
      } else {
        v0 = make_float4(0.f, 0.f, 0.f, 0.f);
        v1 = v0;
      }
      *(float4*)&sA[r][kk] = v0;
      *(float4*)&sA[r][kk + 4] = v1;
    }
    // B tile: 32x128, 16 consecutive floats per thread
    {
      int start = tid * 16;
      int kk = start >> 7, c = start & 127;
      const float4* p = (const float4*)&W[(long)(k0 + kk) * GBv + c];
      float4 b0 = p[0], b1 = p[1], b2 = p[2], b3 = p[3];
      float4* q = (float4*)&sB[kk][c];
      q[0] = b0; q[1] = b1; q[2] = b2; q[3] = b3;
    }
    __syncthreads();
#pragma unroll
    for (int kk = 0; kk < 32; kk++) {
      float av[4];
      av[0] = sA[ty * 4 + 0][kk];
      av[1] = sA[ty * 4 + 1][kk];
      av[2] = sA[ty * 4 + 2][kk];
      av[3] = sA[ty * 4 + 3][kk];
      float4 b0 = *(const float4*)&sB[kk][tx * 8];
      float4 b1 = *(const float4*)&sB[kk][tx * 8 + 4];
      float bv[8] = {b0.x, b0.y, b0.z, b0.w, b1.x, b1.y, b1.z, b1.w};
#pragma unroll
      for (int i = 0; i < 4; i++)
#pragma unroll
        for (int j = 0; j < 8; j++) acc[i][j] += av[i] * bv[j];
    }
    __syncthreads();
  }
#pragma unroll
  for (int i = 0; i < 4; i++) {
    int gr = row0 + ty * 4 + i;
    if (gr < nrows) {
      float dv = dinv[gr];
      float* out = &hws[(long)gr * GBv + tx * 8];
#pragma unroll
      for (int j = 0; j < 8; j++) out[j] = acc[i][j] * dv;
    }
  }
}

// ---------------- CSR aggregate: A[n][c] = dinv[n]*(hws[n][c] + sum_in hws[s][c]) + b[c]

__global__ __launch_bounds__(256) void k_aggregate(const float* __restrict__ hws,
                                                   const int* __restrict__ col,
                                                   const int* __restrict__ offs,
                                                   const float* __restrict__ dinv,
                                                   const float* __restrict__ bias,
                                                   float* __restrict__ A) {
  int n = blockIdx.x * 2 + (threadIdx.x >> 7);
  int c = threadIdx.x & 127;
  if (n >= NN) return;
  int s0 = offs[n], s1 = offs[n + 1];
  float acc = hws[(long)n * GBv + c];
  int j = s0;
  for (; j + 1 < s1; j += 2) {
    int sa = col[j], sb = col[j + 1];
    acc += hws[(long)sa * GBv + c] + hws[(long)sb * GBv + c];
  }
  if (j < s1) acc += hws[(long)col[j] * GBv + c];
  A[(long)n * GBv + c] = acc * dinv[n] + bias[c];
}

// ---------------- elementwise / BN ----------------

__global__ void k_relu(const float* __restrict__ X, float* __restrict__ Y, int total) {
  int i = blockIdx.x * blockDim.x + threadIdx.x;
  int stride = gridDim.x * blockDim.x;
  for (; i < total; i += stride) Y[i] = fmaxf(X[i], 0.f);
}

// blockDim.x == C; st[0..C) = colsum, st[C..2C) = colsumsq
__global__ void k_colstats(const float* __restrict__ X, int rows, float* __restrict__ st) {
  int c = threadIdx.x;
  int C = blockDim.x;
  float s = 0.f, q = 0.f;
  for (int r = blockIdx.x; r < rows; r += gridDim.x) {
    float v = X[(long)r * C + c];
    s += v;
    q += v * v;
  }
  atomicAdd(&st[c], s);
  atomicAdd(&st[C + c], q);
}

__global__ void k_bn_relu(const float* __restrict__ X, const float* __restrict__ st,
                          const float* __restrict__ gamma, const float* __restrict__ beta,
                          float rcpn, int total, int cmask, float* __restrict__ Y) {
  int i = blockIdx.x * blockDim.x + threadIdx.x;
  int stride = gridDim.x * blockDim.x;
  int C = cmask + 1;
  for (; i < total; i += stride) {
    int c = i & cmask;
    float m = st[c] * rcpn;
    float v = st[C + c] * rcpn - m * m;
    float y = (X[i] - m) * rsqrtf(v + 1e-5f) * gamma[c] + beta[c];
    Y[i] = fmaxf(y, 0.f);
  }
}

// ---------------- pooling ----------------

__global__ void k_pool(const float* __restrict__ h, const int* __restrict__ batch,
                       float* __restrict__ hp) {
  int i = blockIdx.x * blockDim.x + threadIdx.x;
  int stride = gridDim.x * blockDim.x;
  for (; i < NN * GBv; i += stride) {
    int n = i >> 7;
    atomicAdd(&hp[(long)batch[n] * GBv + (i & 127)], h[i]);
  }
}

// ---------------- MLP head ----------------

// X: [rows x KIN], W: [KIN x 256], one block per row, 256 threads
template <int KIN, bool RELU>
__global__ __launch_bounds__(256) void k_fc(const float* __restrict__ X,
                                            const float* __restrict__ W,
                                            const float* __restrict__ b,
                                            float* __restrict__ Y) {
  __shared__ float sx[KIN];
  int g = blockIdx.x;
  int c = threadIdx.x;
  for (int k = c; k < KIN; k += 256) sx[k] = X[(long)g * KIN + k];
  __syncthreads();
  float acc = b[c];
#pragma unroll 8
  for (int k = 0; k < KIN; k++) acc += sx[k] * W[(long)k * 256 + c];
  Y[(long)g * 256 + c] = RELU ? fmaxf(acc, 0.f) : acc;
}

// final: out[g][0..2) = X[g] @ Wout + bout ; one wave per graph
__global__ __launch_bounds__(256) void k_out(const float* __restrict__ X,
                                             const float* __restrict__ Wout,
                                             const float* __restrict__ bout,
                                             float* __restrict__ out) {
  int g = blockIdx.x * 4 + (threadIdx.x >> 6);
  int l = threadIdx.x & 63;
  float a0 = 0.f, a1 = 0.f;
  for (int k = l; k < LBv; k += 64) {
    float x = X[(long)g * LBv + k];
    a0 += x * Wout[2 * k];
    a1 += x * Wout[2 * k + 1];
  }
  for (int off = 32; off > 0; off >>= 1) {
    a0 += __shfl_down(a0, off);
    a1 += __shfl_down(a1, off);
  }
  if (l == 0) {
    out[2 * g] = a0 + bout[0];
    out[2 * g + 1] = a1 + bout[1];
  }
}

// ---------------- launch ----------------

extern "C" void kernel_launch(void* const* d_in, const int* in_sizes, int n_in,
                              void* d_out, int out_size, void* d_ws, size_t ws_size,
                              hipStream_t stream) {
  const float* x = (const float*)d_in[0];
  const int* ei = (const int*)d_in[1];      // [2 x E]
  const int* batch = (const int*)d_in[2];   // [N]
  const float* W0 = (const float*)d_in[4];
  const float* b0 = (const float*)d_in[5];
  const float* Wg = (const float*)d_in[6];
  const float* bg = (const float*)d_in[7];
  const float* gamma_g = (const float*)d_in[8];
  const float* beta_g = (const float*)d_in[9];
  const float* Wl0 = (const float*)d_in[10];
  const float* bl0 = (const float*)d_in[11];
  const float* Wl = (const float*)d_in[12];
  const float* bl = (const float*)d_in[13];
  const float* gamma_l = (const float*)d_in[14];
  const float* beta_l = (const float*)d_in[15];
  const float* Wout = (const float*)d_in[16];
  const float* bout = (const float*)d_in[17];
  float* out = (float*)d_out;

  char* w = (char*)d_ws;
  auto alloc = [&](size_t bytes) {
    void* p = (void*)w;
    w += (bytes + 255) & ~(size_t)255;
    return p;
  };
  int* cnt = (int*)alloc((size_t)NN * 4);
  int* offs = (int*)alloc((size_t)(NN + 1) * 4);
  int* cursor = (int*)alloc((size_t)NN * 4);
  int* col = (int*)alloc((size_t)EE * 4);
  float* dinv = (float*)alloc((size_t)NN * 4);
  float* hws = (float*)alloc((size_t)NN * GBv * 4);
  float* A = (float*)alloc((size_t)NN * GBv * 4);
  float* h = (float*)alloc((size_t)NN * GBv * 4);
  float* st = (float*)alloc((size_t)2 * LBv * 4);
  float* hp = (float*)alloc((size_t)GGv * GBv * 4);
  float* m1 = (float*)alloc((size_t)GGv * LBv * 4);
  float* m2 = (float*)alloc((size_t)GGv * LBv * 4);

  // degree + CSR
  hipMemsetAsync(cnt, 0, (size_t)NN * 4, stream);
  k_hist<<<1024, 256, 0, stream>>>(ei + EE, cnt);
  k_dinv<<<(NN + 255) / 256, 256, 0, stream>>>(cnt, dinv);
  k_scan<<<1, 256, 0, stream>>>(cnt, offs);
  hipMemcpyAsync(cursor, offs, (size_t)NN * 4, hipMemcpyDeviceToDevice, stream);
  k_build<<<1024, 256, 0, stream>>>(ei, cursor, col);

  // layer 0: h = relu(gcn(x, W0, b0))
  k_matmul<DINv><<<(NN + 63) / 64, 256, 0, stream>>>(x, W0, dinv, hws, NN);
  k_aggregate<<<(NN + 1) / 2, 256, 0, stream>>>(hws, col, offs, dinv, b0, A);
  k_relu<<<2048, 256, 0, stream>>>(A, h, NN * GBv);

  // layers 1..4: h = relu(bn(gcn(h, Wg[i], bg[i])))
  for (int i = 0; i < GDv; i++) {
    k_matmul<GBv><<<(NN + 63) / 64, 256, 0, stream>>>(h, Wg + (size_t)i * GBv * GBv, dinv, hws, NN);
    k_aggregate<<<(NN + 1) / 2, 256, 0, stream>>>(hws, col, offs, dinv, bg + (size_t)i * GBv, A);
    hipMemsetAsync(st, 0, (size_t)2 * GBv * 4, stream);
    k_colstats<<<1024, GBv, 0, stream>>>(A, NN, st);
    k_bn_relu<<<2048, 256, 0, stream>>>(A, st, gamma_g + (size_t)i * GBv,
                                        beta_g + (size_t)i * GBv, 1.0f / NN, NN * GBv,
                                        GBv - 1, h);
  }

  // pool
  hipMemsetAsync(hp, 0, (size_t)GGv * GBv * 4, stream);
  k_pool<<<25000, 256, 0, stream>>>(h, batch, hp);

  // MLP head
  k_fc<GBv, true><<<GGv, 256, 0, stream>>>(hp, Wl0, bl0, m1);
  for (int i = 0; i < LDv; i++) {
    k_fc<LBv, false><<<GGv, 256, 0, stream>>>(m1, Wl + (size_t)i * LBv * LBv,
                                              bl + (size_t)i * LBv, m2);
    hipMemsetAsync(st, 0, (size_t)2 * LBv * 4, stream);
    k_colstats<<<256, LBv, 0, stream>>>(m2, GGv, st);
    k_bn_relu<<<1024, 256, 0, stream>>>(m2, st, gamma_l + (size_t)i * LBv,
                                        beta_l + (size_t)i * LBv, 1.0f / GGv,
                                        GGv * LBv, LBv - 1, m1);
  }
  k_out<<<GGv / 4, 256, 0, stream>>>(m1, Wout, bout, out);
}

// Round 2
// 975.673 us; speedup vs baseline: 1.2156x; 1.2156x over previous
//
#include <hip/hip_runtime.h>

#define NN 50000
#define EE 640000
#define DINv 64
#define GBv 128
#define GDv 4
#define LBv 256
#define LDv 2
#define GGv 1024

#define SCAN_BLOCKS ((NN + 255) / 256)  // 196

// ---------------- degree / CSR build ----------------

__global__ void k_hist(const int* __restrict__ dst, int* __restrict__ cnt) {
  int i = blockIdx.x * blockDim.x + threadIdx.x;
  int stride = gridDim.x * blockDim.x;
  for (; i < EE; i += stride) atomicAdd(&cnt[dst[i]], 1);
}

__global__ void k_dinv(const int* __restrict__ cnt, float* __restrict__ dinv) {
  int i = blockIdx.x * blockDim.x + threadIdx.x;
  if (i < NN) dinv[i] = 1.0f / sqrtf((float)(cnt[i] + 1));
}

// two-level scan: (1) per-block local exclusive scan + block totals,
// (2) single-block exclusive scan of the 196 totals, (3) uniform add.
__global__ __launch_bounds__(256) void k_scan1(const int* __restrict__ cnt,
                                               int* __restrict__ offs,
                                               int* __restrict__ part) {
  __shared__ int sh[256];
  int tid = threadIdx.x;
  int idx = blockIdx.x * 256 + tid;
  int v = (idx < NN) ? cnt[idx] : 0;
  sh[tid] = v;
  __syncthreads();
  for (int off = 1; off < 256; off <<= 1) {
    int t = (tid >= off) ? sh[tid - off] : 0;
    __syncthreads();
    sh[tid] += t;
    __syncthreads();
  }
  if (idx < NN) offs[idx] = sh[tid] - v;  // local exclusive
  if (tid == 255) part[blockIdx.x] = sh[255];
}

__global__ __launch_bounds__(256) void k_scan2(int* __restrict__ part) {
  __shared__ int sh[256];
  int tid = threadIdx.x;
  int v = (tid < SCAN_BLOCKS) ? part[tid] : 0;
  sh[tid] = v;
  __syncthreads();
  for (int off = 1; off < 256; off <<= 1) {
    int t = (tid >= off) ? sh[tid - off] : 0;
    __syncthreads();
    sh[tid] += t;
    __syncthreads();
  }
  if (tid < SCAN_BLOCKS) part[tid] = sh[tid] - v;  // exclusive
}

__global__ __launch_bounds__(256) void k_scan3(int* __restrict__ offs,
                                               const int* __restrict__ part) {
  int idx = blockIdx.x * 256 + threadIdx.x;
  if (idx < NN) offs[idx] += part[blockIdx.x];
  if (idx == 0) offs[NN] = EE;  // total edge count is static
}

__global__ void k_build(const int* __restrict__ ei, int* __restrict__ cursor,
                        int* __restrict__ col) {
  int i = blockIdx.x * blockDim.x + threadIdx.x;
  int stride = gridDim.x * blockDim.x;
  for (; i < EE; i += stride) {
    int d = ei[EE + i];
    int p = atomicAdd(&cursor[d], 1);
    col[p] = ei[i];
  }
}

// ---------------- dense matmul: hws[r][c] = (h @ W)[r][c] * dinv[r] ----------------

template <int K>
__global__ __launch_bounds__(256) void k_matmul(const float* __restrict__ h,
                                                const float* __restrict__ W,
                                                const float* __restrict__ dinv,
                                                float* __restrict__ hws, int nrows) {
  __shared__ float sA[64][36];
  __shared__ float sB[32][GBv];
  int tid = threadIdx.x;
  int tx = tid & 15;   // col group: cols tx*8 .. +8
  int ty = tid >> 4;   // row group: rows ty*4 .. +4
  int row0 = blockIdx.x * 64;
  float acc[4][8];
#pragma unroll
  for (int i = 0; i < 4; i++)
#pragma unroll
    for (int j = 0; j < 8; j++) acc[i][j] = 0.f;

  for (int k0 = 0; k0 < K; k0 += 32) {
    {
      int start = tid * 8;
      int r = start >> 5, kk = start & 31;
      int gr = row0 + r;
      float4 v0, v1;
      if (gr < nrows) {
        const float* p = &h[(long)gr * K + k0 + kk];
        v0 = *(const float4*)p;
        v1 = *(const float4*)(p + 4);
      } else {
        v0 = make_float4(0.f, 0.f, 0.f, 0.f);
        v1 = v0;
      }
      *(float4*)&sA[r][kk] = v0;
      *(float4*)&sA[r][kk + 4] = v1;
    }
    {
      int start = tid * 16;
      int kk = start >> 7, c = start & 127;
      const float4* p = (const float4*)&W[(long)(k0 + kk) * GBv + c];
      float4 b0 = p[0], b1 = p[1], b2 = p[2], b3 = p[3];
      float4* q = (float4*)&sB[kk][c];
      q[0] = b0; q[1] = b1; q[2] = b2; q[3] = b3;
    }
    __syncthreads();
#pragma unroll
    for (int kk = 0; kk < 32; kk++) {
      float av[4];
      av[0] = sA[ty * 4 + 0][kk];
      av[1] = sA[ty * 4 + 1][kk];
      av[2] = sA[ty * 4 + 2][kk];
      av[3] = sA[ty * 4 + 3][kk];
      float4 b0 = *(const float4*)&sB[kk][tx * 8];
      float4 b1 = *(const float4*)&sB[kk][tx * 8 + 4];
      float bv[8] = {b0.x, b0.y, b0.z, b0.w, b1.x, b1.y, b1.z, b1.w};
#pragma unroll
      for (int i = 0; i < 4; i++)
#pragma unroll
        for (int j = 0; j < 8; j++) acc[i][j] += av[i] * bv[j];
    }
    __syncthreads();
  }
#pragma unroll
  for (int i = 0; i < 4; i++) {
    int gr = row0 + ty * 4 + i;
    if (gr < nrows) {
      float dv = dinv[gr];
      float* out = &hws[(long)gr * GBv + tx * 8];
#pragma unroll
      for (int j = 0; j < 8; j++) out[j] = acc[i][j] * dv;
    }
  }
}

// ---------------- CSR aggregate: A[n][c] = dinv[n]*(hws[n][c] + sum_in hws[s][c]) + b[c]

template <bool RELU>
__global__ __launch_bounds__(256) void k_aggregate(const float* __restrict__ hws,
                                                   const int* __restrict__ col,
                                                   const int* __restrict__ offs,
                                                   const float* __restrict__ dinv,
                                                   const float* __restrict__ bias,
                                                   float* __restrict__ A) {
  int n = blockIdx.x * 2 + (threadIdx.x >> 7);
  int c = threadIdx.x & 127;
  if (n >= NN) return;
  int s0 = offs[n], s1 = offs[n + 1];
  float acc = hws[(long)n * GBv + c];
  int j = s0;
  for (; j + 1 < s1; j += 2) {
    int sa = col[j], sb = col[j + 1];
    acc += hws[(long)sa * GBv + c] + hws[(long)sb * GBv + c];
  }
  if (j < s1) acc += hws[(long)col[j] * GBv + c];
  float y = acc * dinv[n] + bias[c];
  A[(long)n * GBv + c] = RELU ? fmaxf(y, 0.f) : y;
}

// ---------------- BN ----------------

__global__ void k_colstats(const float* __restrict__ X, int rows, float* __restrict__ st) {
  int c = threadIdx.x;
  int C = blockDim.x;
  float s = 0.f, q = 0.f;
  for (int r = blockIdx.x; r < rows; r += gridDim.x) {
    float v = X[(long)r * C + c];
    s += v;
    q += v * v;
  }
  atomicAdd(&st[c], s);
  atomicAdd(&st[C + c], q);
}

__global__ void k_bn_relu(const float* __restrict__ X, const float* __restrict__ st,
                          const float* __restrict__ gamma, const float* __restrict__ beta,
                          float rcpn, int total, int cmask, float* __restrict__ Y) {
  int i = blockIdx.x * blockDim.x + threadIdx.x;
  int stride = gridDim.x * blockDim.x;
  int C = cmask + 1;
  for (; i < total; i += stride) {
    int c = i & cmask;
    float m = st[c] * rcpn;
    float v = st[C + c] * rcpn - m * m;
    float y = (X[i] - m) * rsqrtf(v + 1e-5f) * gamma[c] + beta[c];
    Y[i] = fmaxf(y, 0.f);
  }
}

// ---------------- pooling ----------------

__global__ void k_pool(const float* __restrict__ h, const int* __restrict__ batch,
                       float* __restrict__ hp) {
  int i = blockIdx.x * blockDim.x + threadIdx.x;
  int stride = gridDim.x * blockDim.x;
  for (; i < NN * GBv; i += stride) {
    int n = i >> 7;
    atomicAdd(&hp[(long)batch[n] * GBv + (i & 127)], h[i]);
  }
}

// ---------------- MLP head ----------------

template <int KIN, bool RELU>
__global__ __launch_bounds__(256) void k_fc(const float* __restrict__ X,
                                            const float* __restrict__ W,
                                            const float* __restrict__ b,
                                            float* __restrict__ Y) {
  __shared__ float sx[KIN];
  int g = blockIdx.x;
  int c = threadIdx.x;
  for (int k = c; k < KIN; k += 256) sx[k] = X[(long)g * KIN + k];
  __syncthreads();
  float acc = b[c];
#pragma unroll 8
  for (int k = 0; k < KIN; k++) acc += sx[k] * W[(long)k * 256 + c];
  Y[(long)g * 256 + c] = RELU ? fmaxf(acc, 0.f) : acc;
}

__global__ __launch_bounds__(256) void k_out(const float* __restrict__ X,
                                             const float* __restrict__ Wout,
                                             const float* __restrict__ bout,
                                             float* __restrict__ out) {
  int g = blockIdx.x * 4 + (threadIdx.x >> 6);
  int l = threadIdx.x & 63;
  float a0 = 0.f, a1 = 0.f;
  for (int k = l; k < LBv; k += 64) {
    float x = X[(long)g * LBv + k];
    a0 += x * Wout[2 * k];
    a1 += x * Wout[2 * k + 1];
  }
  for (int off = 32; off > 0; off >>= 1) {
    a0 += __shfl_down(a0, off);
    a1 += __shfl_down(a1, off);
  }
  if (l == 0) {
    out[2 * g] = a0 + bout[0];
    out[2 * g + 1] = a1 + bout[1];
  }
}

// ---------------- launch ----------------

extern "C" void kernel_launch(void* const* d_in, const int* in_sizes, int n_in,
                              void* d_out, int out_size, void* d_ws, size_t ws_size,
                              hipStream_t stream) {
  const float* x = (const float*)d_in[0];
  const int* ei = (const int*)d_in[1];      // [2 x E]
  const int* batch = (const int*)d_in[2];   // [N]
  const float* W0 = (const float*)d_in[4];
  const float* b0 = (const float*)d_in[5];
  const float* Wg = (const float*)d_in[6];
  const float* bg = (const float*)d_in[7];
  const float* gamma_g = (const float*)d_in[8];
  const float* beta_g = (const float*)d_in[9];
  const float* Wl0 = (const float*)d_in[10];
  const float* bl0 = (const float*)d_in[11];
  const float* Wl = (const float*)d_in[12];
  const float* bl = (const float*)d_in[13];
  const float* gamma_l = (const float*)d_in[14];
  const float* beta_l = (const float*)d_in[15];
  const float* Wout = (const float*)d_in[16];
  const float* bout = (const float*)d_in[17];
  float* out = (float*)d_out;

  char* w = (char*)d_ws;
  auto alloc = [&](size_t bytes) {
    void* p = (void*)w;
    w += (bytes + 255) & ~(size_t)255;
    return p;
  };
  int* cnt = (int*)alloc((size_t)NN * 4);
  int* offs = (int*)alloc((size_t)(NN + 1) * 4);
  int* part = (int*)alloc((size_t)SCAN_BLOCKS * 4);
  int* cursor = (int*)alloc((size_t)NN * 4);
  int* col = (int*)alloc((size_t)EE * 4);
  float* dinv = (float*)alloc((size_t)NN * 4);
  float* hws = (float*)alloc((size_t)NN * GBv * 4);
  float* A = (float*)alloc((size_t)NN * GBv * 4);
  float* h = (float*)alloc((size_t)NN * GBv * 4);
  float* st = (float*)alloc((size_t)2 * LBv * 4);
  float* hp = (float*)alloc((size_t)GGv * GBv * 4);
  float* m1 = (float*)alloc((size_t)GGv * LBv * 4);
  float* m2 = (float*)alloc((size_t)GGv * LBv * 4);

  // degree + CSR (two-level parallel scan)
  hipMemsetAsync(cnt, 0, (size_t)NN * 4, stream);
  k_hist<<<1024, 256, 0, stream>>>(ei + EE, cnt);
  k_dinv<<<(NN + 255) / 256, 256, 0, stream>>>(cnt, dinv);
  k_scan1<<<SCAN_BLOCKS, 256, 0, stream>>>(cnt, offs, part);
  k_scan2<<<1, 256, 0, stream>>>(part);
  k_scan3<<<SCAN_BLOCKS, 256, 0, stream>>>(offs, part);
  hipMemcpyAsync(cursor, offs, (size_t)NN * 4, hipMemcpyDeviceToDevice, stream);
  k_build<<<1024, 256, 0, stream>>>(ei, cursor, col);

  // layer 0: h = relu(gcn(x, W0, b0))  (ReLU fused into aggregate)
  k_matmul<DINv><<<(NN + 63) / 64, 256, 0, stream>>>(x, W0, dinv, hws, NN);
  k_aggregate<true><<<(NN + 1) / 2, 256, 0, stream>>>(hws, col, offs, dinv, b0, h);

  // layers 1..4: h = relu(bn(gcn(h, Wg[i], bg[i])))
  for (int i = 0; i < GDv; i++) {
    k_matmul<GBv><<<(NN + 63) / 64, 256, 0, stream>>>(h, Wg + (size_t)i * GBv * GBv, dinv, hws, NN);
    k_aggregate<false><<<(NN + 1) / 2, 256, 0, stream>>>(hws, col, offs, dinv, bg + (size_t)i * GBv, A);
    hipMemsetAsync(st, 0, (size_t)2 * GBv * 4, stream);
    k_colstats<<<1024, GBv, 0, stream>>>(A, NN, st);
    k_bn_relu<<<2048, 256, 0, stream>>>(A, st, gamma_g + (size_t)i * GBv,
                                        beta_g + (size_t)i * GBv, 1.0f / NN, NN * GBv,
                                        GBv - 1, h);
  }

  // pool
  hipMemsetAsync(hp, 0, (size_t)GGv * GBv * 4, stream);
  k_pool<<<25000, 256, 0, stream>>>(h, batch, hp);

  // MLP head
  k_fc<GBv, true><<<GGv, 256, 0, stream>>>(hp, Wl0, bl0, m1);
  for (int i = 0; i < LDv; i++) {
    k_fc<LBv, false><<<GGv, 256, 0, stream>>>(m1, Wl + (size_t)i * LBv * LBv,
                                              bl + (size_t)i * LBv, m2);
    hipMemsetAsync(st, 0, (size_t)2 * LBv * 4, stream);
    k_colstats<<<256, LBv, 0, stream>>>(m2, GGv, st);
    k_bn_relu<<<1024, 256, 0, stream>>>(m2, st, gamma_l + (size_t)i * LBv,
                                        beta_l + (size_t)i * LBv, 1.0f / GGv,
                                        GGv * LBv, LBv - 1, m1);
  }
  k_out<<<GGv / 4, 256, 0, stream>>>(m1, Wout, bout, out);
}

// Round 3
// 747.822 us; speedup vs baseline: 1.5860x; 1.3047x over previous
//
#include <hip/hip_runtime.h>
#include <hip/hip_bf16.h>

#define NN 50000
#define EE 640000
#define DINv 64
#define GBv 128
#define GDv 4
#define LBv 256
#define LDv 2
#define GGv 1024

#define SCAN_BLOCKS ((NN + 255) / 256)  // 196

// ---------------- degree / CSR build ----------------

__global__ void k_hist(const int* __restrict__ dst, int* __restrict__ cnt) {
  int i = blockIdx.x * blockDim.x + threadIdx.x;
  int stride = gridDim.x * blockDim.x;
  for (; i < EE; i += stride) atomicAdd(&cnt[dst[i]], 1);
}

__global__ void k_dinv(const int* __restrict__ cnt, float* __restrict__ dinv) {
  int i = blockIdx.x * blockDim.x + threadIdx.x;
  if (i < NN) dinv[i] = 1.0f / sqrtf((float)(cnt[i] + 1));
}

__global__ __launch_bounds__(256) void k_scan1(const int* __restrict__ cnt,
                                               int* __restrict__ offs,
                                               int* __restrict__ part) {
  __shared__ int sh[256];
  int tid = threadIdx.x;
  int idx = blockIdx.x * 256 + tid;
  int v = (idx < NN) ? cnt[idx] : 0;
  sh[tid] = v;
  __syncthreads();
  for (int off = 1; off < 256; off <<= 1) {
    int t = (tid >= off) ? sh[tid - off] : 0;
    __syncthreads();
    sh[tid] += t;
    __syncthreads();
  }
  if (idx < NN) offs[idx] = sh[tid] - v;  // local exclusive
  if (tid == 255) part[blockIdx.x] = sh[255];
}

__global__ __launch_bounds__(256) void k_scan2(int* __restrict__ part) {
  __shared__ int sh[256];
  int tid = threadIdx.x;
  int v = (tid < SCAN_BLOCKS) ? part[tid] : 0;
  sh[tid] = v;
  __syncthreads();
  for (int off = 1; off < 256; off <<= 1) {
    int t = (tid >= off) ? sh[tid - off] : 0;
    __syncthreads();
    sh[tid] += t;
    __syncthreads();
  }
  if (tid < SCAN_BLOCKS) part[tid] = sh[tid] - v;  // exclusive
}

__global__ __launch_bounds__(256) void k_scan3(int* __restrict__ offs,
                                               const int* __restrict__ part) {
  int idx = blockIdx.x * 256 + threadIdx.x;
  if (idx < NN) offs[idx] += part[blockIdx.x];
  if (idx == 0) offs[NN] = EE;
}

__global__ void k_build(const int* __restrict__ ei, int* __restrict__ cursor,
                        int* __restrict__ col) {
  int i = blockIdx.x * blockDim.x + threadIdx.x;
  int stride = gridDim.x * blockDim.x;
  for (; i < EE; i += stride) {
    int d = ei[EE + i];
    int p = atomicAdd(&cursor[d], 1);
    col[p] = ei[i];
  }
}

// ---------------- dense matmul: hws[r][c] = bf16((h @ W)[r][c] * dinv[r]) ----------------

template <int K>
__global__ __launch_bounds__(256) void k_matmul(const float* __restrict__ h,
                                                const float* __restrict__ W,
                                                const float* __restrict__ dinv,
                                                __hip_bfloat16* __restrict__ hws,
                                                int nrows) {
  __shared__ float sA[64][36];
  __shared__ float sB[32][GBv];
  int tid = threadIdx.x;
  int tx = tid & 15;   // col group: cols tx*8 .. +8
  int ty = tid >> 4;   // row group: rows ty*4 .. +4
  int row0 = blockIdx.x * 64;
  float acc[4][8];
#pragma unroll
  for (int i = 0; i < 4; i++)
#pragma unroll
    for (int j = 0; j < 8; j++) acc[i][j] = 0.f;

  for (int k0 = 0; k0 < K; k0 += 32) {
    {
      int start = tid * 8;
      int r = start >> 5, kk = start & 31;
      int gr = row0 + r;
      float4 v0, v1;
      if (gr < nrows) {
        const float* p = &h[(long)gr * K + k0 + kk];
        v0 = *(const float4*)p;
        v1 = *(const float4*)(p + 4);
      } else {
        v0 = make_float4(0.f, 0.f, 0.f, 0.f);
        v1 = v0;
      }
      *(float4*)&sA[r][kk] = v0;
      *(float4*)&sA[r][kk + 4] = v1;
    }
    {
      int start = tid * 16;
      int kk = start >> 7, c = start & 127;
      const float4* p = (const float4*)&W[(long)(k0 + kk) * GBv + c];
      float4 b0 = p[0], b1 = p[1], b2 = p[2], b3 = p[3];
      float4* q = (float4*)&sB[kk][c];
      q[0] = b0; q[1] = b1; q[2] = b2; q[3] = b3;
    }
    __syncthreads();
#pragma unroll
    for (int kk = 0; kk < 32; kk++) {
      float av[4];
      av[0] = sA[ty * 4 + 0][kk];
      av[1] = sA[ty * 4 + 1][kk];
      av[2] = sA[ty * 4 + 2][kk];
      av[3] = sA[ty * 4 + 3][kk];
      float4 b0 = *(const float4*)&sB[kk][tx * 8];
      float4 b1 = *(const float4*)&sB[kk][tx * 8 + 4];
      float bv[8] = {b0.x, b0.y, b0.z, b0.w, b1.x, b1.y, b1.z, b1.w};
#pragma unroll
      for (int i = 0; i < 4; i++)
#pragma unroll
        for (int j = 0; j < 8; j++) acc[i][j] += av[i] * bv[j];
    }
    __syncthreads();
  }
#pragma unroll
  for (int i = 0; i < 4; i++) {
    int gr = row0 + ty * 4 + i;
    if (gr < nrows) {
      float dv = dinv[gr];
      union { __hip_bfloat16 b[8]; float4 f; } tmp;
#pragma unroll
      for (int j = 0; j < 8; j++) tmp.b[j] = __float2bfloat16(acc[i][j] * dv);
      *(float4*)&hws[(long)gr * GBv + tx * 8] = tmp.f;
    }
  }
}

// ---------------- CSR aggregate: A[n][c] = dinv[n]*(hws[n][c] + sum_in hws[s][c]) + b[c]
// 1 wave per node: 64 lanes x ushort2 (2 bf16 cols/lane) covers the 128-col row
// in one load instruction; edge loop unrolled x4 for MLP.

__device__ __forceinline__ float2 bf2x(ushort2 v) {
  float2 r;
  r.x = __uint_as_float((unsigned)v.x << 16);
  r.y = __uint_as_float((unsigned)v.y << 16);
  return r;
}

template <bool RELU>
__global__ __launch_bounds__(256) void k_aggregate(const ushort2* __restrict__ H,
                                                   const int* __restrict__ col,
                                                   const int* __restrict__ offs,
                                                   const float* __restrict__ dinv,
                                                   const float* __restrict__ bias,
                                                   float* __restrict__ A) {
  int n = blockIdx.x * 4 + (threadIdx.x >> 6);  // 12500 blocks * 4 = 50000 exactly
  int lane = threadIdx.x & 63;
  int s0 = offs[n], s1 = offs[n + 1];
  float2 self = bf2x(H[(long)n * 64 + lane]);
  float a0 = self.x, a1 = self.y;
  int j = s0;
  for (; j + 3 < s1; j += 4) {
    int sa = col[j], sb = col[j + 1], sc = col[j + 2], sd = col[j + 3];
    float2 va = bf2x(H[(long)sa * 64 + lane]);
    float2 vb = bf2x(H[(long)sb * 64 + lane]);
    float2 vc = bf2x(H[(long)sc * 64 + lane]);
    float2 vd = bf2x(H[(long)sd * 64 + lane]);
    a0 += (va.x + vb.x) + (vc.x + vd.x);
    a1 += (va.y + vb.y) + (vc.y + vd.y);
  }
  for (; j < s1; j++) {
    float2 v = bf2x(H[(long)col[j] * 64 + lane]);
    a0 += v.x;
    a1 += v.y;
  }
  float d = dinv[n];
  float2 bi = *(const float2*)&bias[lane * 2];
  float y0 = a0 * d + bi.x;
  float y1 = a1 * d + bi.y;
  if (RELU) {
    y0 = fmaxf(y0, 0.f);
    y1 = fmaxf(y1, 0.f);
  }
  ((float2*)A)[(long)n * 64 + lane] = make_float2(y0, y1);
}

// ---------------- BN ----------------

__global__ void k_colstats(const float* __restrict__ X, int rows, float* __restrict__ st) {
  int c = threadIdx.x;
  int C = blockDim.x;
  float s = 0.f, q = 0.f;
  for (int r = blockIdx.x; r < rows; r += gridDim.x) {
    float v = X[(long)r * C + c];
    s += v;
    q += v * v;
  }
  atomicAdd(&st[c], s);
  atomicAdd(&st[C + c], q);
}

__global__ void k_bn_relu(const float* __restrict__ X, const float* __restrict__ st,
                          const float* __restrict__ gamma, const float* __restrict__ beta,
                          float rcpn, int total, int cmask, float* __restrict__ Y) {
  int i = blockIdx.x * blockDim.x + threadIdx.x;
  int stride = gridDim.x * blockDim.x;
  int C = cmask + 1;
  for (; i < total; i += stride) {
    int c = i & cmask;
    float m = st[c] * rcpn;
    float v = st[C + c] * rcpn - m * m;
    float y = (X[i] - m) * rsqrtf(v + 1e-5f) * gamma[c] + beta[c];
    Y[i] = fmaxf(y, 0.f);
  }
}

// ---------------- pooling ----------------

__global__ void k_pool(const float* __restrict__ h, const int* __restrict__ batch,
                       float* __restrict__ hp) {
  int i = blockIdx.x * blockDim.x + threadIdx.x;
  int stride = gridDim.x * blockDim.x;
  for (; i < NN * GBv; i += stride) {
    int n = i >> 7;
    atomicAdd(&hp[(long)batch[n] * GBv + (i & 127)], h[i]);
  }
}

// ---------------- MLP head ----------------

template <int KIN, bool RELU>
__global__ __launch_bounds__(256) void k_fc(const float* __restrict__ X,
                                            const float* __restrict__ W,
                                            const float* __restrict__ b,
                                            float* __restrict__ Y) {
  __shared__ float sx[KIN];
  int g = blockIdx.x;
  int c = threadIdx.x;
  for (int k = c; k < KIN; k += 256) sx[k] = X[(long)g * KIN + k];
  __syncthreads();
  float acc = b[c];
#pragma unroll 8
  for (int k = 0; k < KIN; k++) acc += sx[k] * W[(long)k * 256 + c];
  Y[(long)g * 256 + c] = RELU ? fmaxf(acc, 0.f) : acc;
}

__global__ __launch_bounds__(256) void k_out(const float* __restrict__ X,
                                             const float* __restrict__ Wout,
                                             const float* __restrict__ bout,
                                             float* __restrict__ out) {
  int g = blockIdx.x * 4 + (threadIdx.x >> 6);
  int l = threadIdx.x & 63;
  float a0 = 0.f, a1 = 0.f;
  for (int k = l; k < LBv; k += 64) {
    float x = X[(long)g * LBv + k];
    a0 += x * Wout[2 * k];
    a1 += x * Wout[2 * k + 1];
  }
  for (int off = 32; off > 0; off >>= 1) {
    a0 += __shfl_down(a0, off);
    a1 += __shfl_down(a1, off);
  }
  if (l == 0) {
    out[2 * g] = a0 + bout[0];
    out[2 * g + 1] = a1 + bout[1];
  }
}

// ---------------- launch ----------------

extern "C" void kernel_launch(void* const* d_in, const int* in_sizes, int n_in,
                              void* d_out, int out_size, void* d_ws, size_t ws_size,
                              hipStream_t stream) {
  const float* x = (const float*)d_in[0];
  const int* ei = (const int*)d_in[1];      // [2 x E]
  const int* batch = (const int*)d_in[2];   // [N]
  const float* W0 = (const float*)d_in[4];
  const float* b0 = (const float*)d_in[5];
  const float* Wg = (const float*)d_in[6];
  const float* bg = (const float*)d_in[7];
  const float* gamma_g = (const float*)d_in[8];
  const float* beta_g = (const float*)d_in[9];
  const float* Wl0 = (const float*)d_in[10];
  const float* bl0 = (const float*)d_in[11];
  const float* Wl = (const float*)d_in[12];
  const float* bl = (const float*)d_in[13];
  const float* gamma_l = (const float*)d_in[14];
  const float* beta_l = (const float*)d_in[15];
  const float* Wout = (const float*)d_in[16];
  const float* bout = (const float*)d_in[17];
  float* out = (float*)d_out;

  char* w = (char*)d_ws;
  auto alloc = [&](size_t bytes) {
    void* p = (void*)w;
    w += (bytes + 255) & ~(size_t)255;
    return p;
  };
  int* cnt = (int*)alloc((size_t)NN * 4);
  int* offs = (int*)alloc((size_t)(NN + 1) * 4);
  int* part = (int*)alloc((size_t)SCAN_BLOCKS * 4);
  int* cursor = (int*)alloc((size_t)NN * 4);
  int* col = (int*)alloc((size_t)EE * 4);
  float* dinv = (float*)alloc((size_t)NN * 4);
  __hip_bfloat16* hws = (__hip_bfloat16*)alloc((size_t)NN * GBv * 2);
  float* A = (float*)alloc((size_t)NN * GBv * 4);
  float* h = (float*)alloc((size_t)NN * GBv * 4);
  float* st = (float*)alloc((size_t)2 * LBv * 4);
  float* hp = (float*)alloc((size_t)GGv * GBv * 4);
  float* m1 = (float*)alloc((size_t)GGv * LBv * 4);
  float* m2 = (float*)alloc((size_t)GGv * LBv * 4);

  // degree + CSR (two-level parallel scan)
  hipMemsetAsync(cnt, 0, (size_t)NN * 4, stream);
  k_hist<<<1024, 256, 0, stream>>>(ei + EE, cnt);
  k_dinv<<<(NN + 255) / 256, 256, 0, stream>>>(cnt, dinv);
  k_scan1<<<SCAN_BLOCKS, 256, 0, stream>>>(cnt, offs, part);
  k_scan2<<<1, 256, 0, stream>>>(part);
  k_scan3<<<SCAN_BLOCKS, 256, 0, stream>>>(offs, part);
  hipMemcpyAsync(cursor, offs, (size_t)NN * 4, hipMemcpyDeviceToDevice, stream);
  k_build<<<1024, 256, 0, stream>>>(ei, cursor, col);

  // layer 0: h = relu(gcn(x, W0, b0))  (ReLU fused into aggregate)
  k_matmul<DINv><<<(NN + 63) / 64, 256, 0, stream>>>(x, W0, dinv, hws, NN);
  k_aggregate<true><<<NN / 4, 256, 0, stream>>>((const ushort2*)hws, col, offs, dinv, b0, h);

  // layers 1..4: h = relu(bn(gcn(h, Wg[i], bg[i])))
  for (int i = 0; i < GDv; i++) {
    k_matmul<GBv><<<(NN + 63) / 64, 256, 0, stream>>>(h, Wg + (size_t)i * GBv * GBv, dinv, hws, NN);
    k_aggregate<false><<<NN / 4, 256, 0, stream>>>((const ushort2*)hws, col, offs, dinv,
                                                   bg + (size_t)i * GBv, A);
    hipMemsetAsync(st, 0, (size_t)2 * GBv * 4, stream);
    k_colstats<<<1024, GBv, 0, stream>>>(A, NN, st);
    k_bn_relu<<<2048, 256, 0, stream>>>(A, st, gamma_g + (size_t)i * GBv,
                                        beta_g + (size_t)i * GBv, 1.0f / NN, NN * GBv,
                                        GBv - 1, h);
  }

  // pool
  hipMemsetAsync(hp, 0, (size_t)GGv * GBv * 4, stream);
  k_pool<<<25000, 256, 0, stream>>>(h, batch, hp);

  // MLP head
  k_fc<GBv, true><<<GGv, 256, 0, stream>>>(hp, Wl0, bl0, m1);
  for (int i = 0; i < LDv; i++) {
    k_fc<LBv, false><<<GGv, 256, 0, stream>>>(m1, Wl + (size_t)i * LBv * LBv,
                                              bl + (size_t)i * LBv, m2);
    hipMemsetAsync(st, 0, (size_t)2 * LBv * 4, stream);
    k_colstats<<<256, LBv, 0, stream>>>(m2, GGv, st);
    k_bn_relu<<<1024, 256, 0, stream>>>(m2, st, gamma_l + (size_t)i * LBv,
                                        beta_l + (size_t)i * LBv, 1.0f / GGv,
                                        GGv * LBv, LBv - 1, m1);
  }
  k_out<<<GGv / 4, 256, 0, stream>>>(m1, Wout, bout, out);
}

// Round 4
// 677.737 us; speedup vs baseline: 1.7500x; 1.1034x over previous
//
#include <hip/hip_runtime.h>

#define NN 50000
#define EE 640000
#define DINv 64
#define GBv 128
#define GDv 4
#define LBv 256
#define LDv 2
#define GGv 1024

#define SCAN_BLOCKS ((NN + 255) / 256)  // 196

typedef _Float16 f16x8 __attribute__((ext_vector_type(8)));
typedef float f32x4 __attribute__((ext_vector_type(4)));

__device__ __forceinline__ float h2f(ushort u) {
  union { ushort u; _Float16 h; } x;
  x.u = u;
  return (float)x.h;
}
__device__ __forceinline__ ushort f2h(float f) {
  union { ushort u; _Float16 h; } x;
  x.h = (_Float16)f;
  return x.u;
}

// ---------------- degree / CSR build ----------------

__global__ void k_hist(const int* __restrict__ dst, int* __restrict__ cnt) {
  int i = blockIdx.x * blockDim.x + threadIdx.x;
  int stride = gridDim.x * blockDim.x;
  for (; i < EE; i += stride) atomicAdd(&cnt[dst[i]], 1);
}

__global__ void k_dinv(const int* __restrict__ cnt, float* __restrict__ dinv) {
  int i = blockIdx.x * blockDim.x + threadIdx.x;
  if (i < NN) dinv[i] = 1.0f / sqrtf((float)(cnt[i] + 1));
}

__global__ __launch_bounds__(256) void k_scan1(const int* __restrict__ cnt,
                                               int* __restrict__ offs,
                                               int* __restrict__ part) {
  __shared__ int sh[256];
  int tid = threadIdx.x;
  int idx = blockIdx.x * 256 + tid;
  int v = (idx < NN) ? cnt[idx] : 0;
  sh[tid] = v;
  __syncthreads();
  for (int off = 1; off < 256; off <<= 1) {
    int t = (tid >= off) ? sh[tid - off] : 0;
    __syncthreads();
    sh[tid] += t;
    __syncthreads();
  }
  if (idx < NN) offs[idx] = sh[tid] - v;
  if (tid == 255) part[blockIdx.x] = sh[255];
}

__global__ __launch_bounds__(256) void k_scan2(int* __restrict__ part) {
  __shared__ int sh[256];
  int tid = threadIdx.x;
  int v = (tid < SCAN_BLOCKS) ? part[tid] : 0;
  sh[tid] = v;
  __syncthreads();
  for (int off = 1; off < 256; off <<= 1) {
    int t = (tid >= off) ? sh[tid - off] : 0;
    __syncthreads();
    sh[tid] += t;
    __syncthreads();
  }
  if (tid < SCAN_BLOCKS) part[tid] = sh[tid] - v;
}

__global__ __launch_bounds__(256) void k_scan3(int* __restrict__ offs,
                                               const int* __restrict__ part) {
  int idx = blockIdx.x * 256 + threadIdx.x;
  if (idx < NN) offs[idx] += part[blockIdx.x];
  if (idx == 0) offs[NN] = EE;
}

__global__ void k_build(const int* __restrict__ ei, int* __restrict__ cursor,
                        int* __restrict__ col) {
  int i = blockIdx.x * blockDim.x + threadIdx.x;
  int stride = gridDim.x * blockDim.x;
  for (; i < EE; i += stride) {
    int d = ei[EE + i];
    int p = atomicAdd(&cursor[d], 1);
    col[p] = ei[i];
  }
}

// ---------------- weight transpose+convert: Wt[c][k] = f16(W[k][c]) ----------------

__global__ void k_convW(const float* __restrict__ W0, const float* __restrict__ Wg,
                        ushort* __restrict__ Wt0, ushort* __restrict__ Wtg) {
  int idx = blockIdx.x * 256 + threadIdx.x;
  if (idx < DINv * GBv) {  // W0: [64][128] -> Wt0[c*64+k]
    int c = idx >> 6, k = idx & 63;
    Wt0[idx] = f2h(W0[k * GBv + c]);
  } else if (idx < DINv * GBv + GDv * GBv * GBv) {
    int e = idx - DINv * GBv;
    int i = e >> 14, rem = e & 16383;
    int c = rem >> 7, k = rem & 127;
    Wtg[e] = f2h(Wg[i * GBv * GBv + k * GBv + c]);
  }
}

// ---------------- MFMA matmul: hws[r][c] = f16((bn_relu?(X) @ W)[r][c] * dinv[r]) ----
// MODE 0: X fp32 [NN][64], plain.  MODE 1: X f16 [NN][128], plain.
// MODE 2: X f16 [NN][128], apply y=relu(x*s_c+t_c) on load (BN fold).

template <int K, int MODE>
__global__ __launch_bounds__(256) void k_mm(const void* __restrict__ Xin,
                                            const ushort* __restrict__ Wt,
                                            const float* __restrict__ st,
                                            const float* __restrict__ gamma,
                                            const float* __restrict__ beta, float rcpn,
                                            const float* __restrict__ dinv,
                                            ushort* __restrict__ hws) {
  __shared__ __attribute__((aligned(16))) _Float16 sW[128 * K];
  __shared__ __attribute__((aligned(16))) _Float16 sA[64 * K];
  __shared__ float sS[128], sT[128];
  int tid = threadIdx.x;
  int row0 = blockIdx.x * 64;

  // stage Wt (straight copy, 128*K halfs)
  {
    const uint4* src = (const uint4*)Wt;
    uint4* dst = (uint4*)sW;
    int n4 = 128 * K / 8;
    for (int i = tid; i < n4; i += 256) dst[i] = src[i];
  }
  if constexpr (MODE == 2) {
    if (tid < 128) {
      int c = tid;
      float m = st[c] * rcpn;
      float v = st[128 + c] * rcpn - m * m;
      float s = rsqrtf(v + 1e-5f) * gamma[c];
      sS[c] = s;
      sT[c] = beta[c] - m * s;
    }
  }
  __syncthreads();

  // stage A tile (64 rows x K)
  if constexpr (MODE == 0) {
    int r = tid >> 2, col0 = (tid & 3) * 16;
    int gr = row0 + r;
    const float* p = (const float*)Xin + (long)gr * K + col0;
    union { uint4 v[2]; ushort us[16]; } o;
#pragma unroll
    for (int j = 0; j < 16; j++) o.us[j] = (gr < NN) ? f2h(p[j]) : (ushort)0;
    *(uint4*)&sA[r * K + col0] = o.v[0];
    *(uint4*)&sA[r * K + col0 + 8] = o.v[1];
  } else {
    int r = tid >> 2, col0 = (tid & 3) * 32;
    int gr = row0 + r;
    const uint4* p = (const uint4*)((const ushort*)Xin + (long)gr * 128 + col0);
#pragma unroll
    for (int ch = 0; ch < 4; ch++) {
      union { uint4 v; ushort us[8]; } o;
      o.v = (gr < NN) ? p[ch] : make_uint4(0, 0, 0, 0);
      if constexpr (MODE == 2) {
#pragma unroll
        for (int j = 0; j < 8; j++) {
          int c = col0 + ch * 8 + j;
          o.us[j] = f2h(fmaxf(h2f(o.us[j]) * sS[c] + sT[c], 0.f));
        }
      }
      if constexpr (MODE == 1) {
        if (gr >= NN) o.v = make_uint4(0, 0, 0, 0);
      }
      *(uint4*)&sA[r * K + col0 + ch * 8] = o.v;
    }
  }
  __syncthreads();

  // compute: wave w -> rows 16w..16w+16, all 128 cols (8 col-tiles)
  int w = tid >> 6, lane = tid & 63;
  int m = lane & 15, quad = lane >> 4;
  f32x4 acc[8];
#pragma unroll
  for (int ct = 0; ct < 8; ct++) acc[ct] = (f32x4){0.f, 0.f, 0.f, 0.f};
  const _Float16* pa = &sA[(16 * w + m) * K + quad * 8];
#pragma unroll
  for (int ks = 0; ks < K; ks += 32) {
    f16x8 a = *(const f16x8*)(pa + ks);
#pragma unroll
    for (int ct = 0; ct < 8; ct++) {
      f16x8 b = *(const f16x8*)&sW[(ct * 16 + m) * K + ks + quad * 8];
      acc[ct] = __builtin_amdgcn_mfma_f32_16x16x32_f16(a, b, acc[ct], 0, 0, 0);
    }
  }
  __syncthreads();

  // C -> LDS (reuse sA for K=128, sW for K=64), scaled by dinv
  _Float16* P = (K == 128) ? sA : sW;
  int crow = 16 * w + quad * 4;
  float dv[4];
#pragma unroll
  for (int r = 0; r < 4; r++) {
    int gr = row0 + crow + r;
    dv[r] = (gr < NN) ? dinv[gr] : 0.f;
  }
#pragma unroll
  for (int ct = 0; ct < 8; ct++)
#pragma unroll
    for (int r = 0; r < 4; r++)
      P[(crow + r) * 128 + ct * 16 + m] = (_Float16)(acc[ct][r] * dv[r]);
  __syncthreads();

  // coalesced store
  {
    int r = tid >> 2, col0 = (tid & 3) * 32;
    int gr = row0 + r;
    if (gr < NN) {
      const uint4* src = (const uint4*)&P[r * 128 + col0];
      uint4* dst = (uint4*)&hws[(long)gr * 128 + col0];
#pragma unroll
      for (int ch = 0; ch < 4; ch++) dst[ch] = src[ch];
    }
  }
}

// ---------------- CSR aggregate (f16 in / f16 out) ----------------

template <bool RELU>
__global__ __launch_bounds__(256) void k_aggregate(const ushort2* __restrict__ H,
                                                   const int* __restrict__ col,
                                                   const int* __restrict__ offs,
                                                   const float* __restrict__ dinv,
                                                   const float* __restrict__ bias,
                                                   ushort2* __restrict__ A) {
  int n = blockIdx.x * 4 + (threadIdx.x >> 6);
  int lane = threadIdx.x & 63;
  int s0 = offs[n], s1 = offs[n + 1];
  ushort2 self = H[(long)n * 64 + lane];
  float a0 = h2f(self.x), a1 = h2f(self.y);
  int j = s0;
  for (; j + 3 < s1; j += 4) {
    int sa = col[j], sb = col[j + 1], sc = col[j + 2], sd = col[j + 3];
    ushort2 va = H[(long)sa * 64 + lane];
    ushort2 vb = H[(long)sb * 64 + lane];
    ushort2 vc = H[(long)sc * 64 + lane];
    ushort2 vd = H[(long)sd * 64 + lane];
    a0 += (h2f(va.x) + h2f(vb.x)) + (h2f(vc.x) + h2f(vd.x));
    a1 += (h2f(va.y) + h2f(vb.y)) + (h2f(vc.y) + h2f(vd.y));
  }
  for (; j < s1; j++) {
    ushort2 v = H[(long)col[j] * 64 + lane];
    a0 += h2f(v.x);
    a1 += h2f(v.y);
  }
  float d = dinv[n];
  float2 bi = *(const float2*)&bias[lane * 2];
  float y0 = a0 * d + bi.x;
  float y1 = a1 * d + bi.y;
  if (RELU) {
    y0 = fmaxf(y0, 0.f);
    y1 = fmaxf(y1, 0.f);
  }
  ushort2 o;
  o.x = f2h(y0);
  o.y = f2h(y1);
  A[(long)n * 64 + lane] = o;
}

// ---------------- column stats ----------------

// f16 input, C=128, blockDim=128
__global__ void k_colstats_h(const ushort* __restrict__ X, float* __restrict__ st) {
  int c = threadIdx.x;
  float s = 0.f, q = 0.f;
  for (int r = blockIdx.x; r < NN; r += gridDim.x) {
    float v = h2f(X[(long)r * 128 + c]);
    s += v;
    q += v * v;
  }
  atomicAdd(&st[c], s);
  atomicAdd(&st[128 + c], q);
}

// fp32 input, C=blockDim
__global__ void k_colstats(const float* __restrict__ X, int rows, float* __restrict__ st) {
  int c = threadIdx.x;
  int C = blockDim.x;
  float s = 0.f, q = 0.f;
  for (int r = blockIdx.x; r < rows; r += gridDim.x) {
    float v = X[(long)r * C + c];
    s += v;
    q += v * v;
  }
  atomicAdd(&st[c], s);
  atomicAdd(&st[C + c], q);
}

// ---------------- pool with fused BN+relu ----------------

__global__ __launch_bounds__(256) void k_pool_bn(const ushort* __restrict__ A,
                                                 const float* __restrict__ st,
                                                 const float* __restrict__ gamma,
                                                 const float* __restrict__ beta,
                                                 const int* __restrict__ batch,
                                                 float* __restrict__ hp) {
  __shared__ float sS[128], sT[128];
  if (threadIdx.x < 128) {
    int c = threadIdx.x;
    float m = st[c] * (1.f / NN);
    float v = st[128 + c] * (1.f / NN) - m * m;
    float s = rsqrtf(v + 1e-5f) * gamma[c];
    sS[c] = s;
    sT[c] = beta[c] - m * s;
  }
  __syncthreads();
  int i = blockIdx.x * 256 + threadIdx.x;
  int stride = gridDim.x * 256;
  for (; i < NN * 128; i += stride) {
    int n = i >> 7, c = i & 127;
    float y = fmaxf(h2f(A[i]) * sS[c] + sT[c], 0.f);
    atomicAdd(&hp[(long)batch[n] * 128 + c], y);
  }
}

// ---------------- MLP head ----------------
// MODE 0: plain in + relu out; 1: plain in, no relu; 2: BN+relu on in, no relu out

template <int KIN, int MODE>
__global__ __launch_bounds__(256) void k_fc(const float* __restrict__ X,
                                            const float* __restrict__ W,
                                            const float* __restrict__ b,
                                            const float* __restrict__ st,
                                            const float* __restrict__ gamma,
                                            const float* __restrict__ beta,
                                            float* __restrict__ Y) {
  __shared__ float sx[KIN];
  int g = blockIdx.x;
  int c = threadIdx.x;
  for (int k = c; k < KIN; k += 256) {
    float v = X[(long)g * KIN + k];
    if constexpr (MODE == 2) {
      float m = st[k] * (1.f / GGv);
      float var = st[KIN + k] * (1.f / GGv) - m * m;
      v = fmaxf((v - m) * rsqrtf(var + 1e-5f) * gamma[k] + beta[k], 0.f);
    }
    sx[k] = v;
  }
  __syncthreads();
  float acc = b[c];
#pragma unroll 8
  for (int k = 0; k < KIN; k++) acc += sx[k] * W[(long)k * 256 + c];
  Y[(long)g * 256 + c] = (MODE == 0) ? fmaxf(acc, 0.f) : acc;
}

__global__ __launch_bounds__(256) void k_out(const float* __restrict__ X,
                                             const float* __restrict__ st,
                                             const float* __restrict__ gamma,
                                             const float* __restrict__ beta,
                                             const float* __restrict__ Wout,
                                             const float* __restrict__ bout,
                                             float* __restrict__ out) {
  int g = blockIdx.x * 4 + (threadIdx.x >> 6);
  int l = threadIdx.x & 63;
  float a0 = 0.f, a1 = 0.f;
  for (int k = l; k < LBv; k += 64) {
    float z = X[(long)g * LBv + k];
    float m = st[k] * (1.f / GGv);
    float var = st[LBv + k] * (1.f / GGv) - m * m;
    float x = fmaxf((z - m) * rsqrtf(var + 1e-5f) * gamma[k] + beta[k], 0.f);
    a0 += x * Wout[2 * k];
    a1 += x * Wout[2 * k + 1];
  }
  for (int off = 32; off > 0; off >>= 1) {
    a0 += __shfl_down(a0, off);
    a1 += __shfl_down(a1, off);
  }
  if (l == 0) {
    out[2 * g] = a0 + bout[0];
    out[2 * g + 1] = a1 + bout[1];
  }
}

// ---------------- launch ----------------

extern "C" void kernel_launch(void* const* d_in, const int* in_sizes, int n_in,
                              void* d_out, int out_size, void* d_ws, size_t ws_size,
                              hipStream_t stream) {
  const float* x = (const float*)d_in[0];
  const int* ei = (const int*)d_in[1];
  const int* batch = (const int*)d_in[2];
  const float* W0 = (const float*)d_in[4];
  const float* b0 = (const float*)d_in[5];
  const float* Wg = (const float*)d_in[6];
  const float* bg = (const float*)d_in[7];
  const float* gamma_g = (const float*)d_in[8];
  const float* beta_g = (const float*)d_in[9];
  const float* Wl0 = (const float*)d_in[10];
  const float* bl0 = (const float*)d_in[11];
  const float* Wl = (const float*)d_in[12];
  const float* bl = (const float*)d_in[13];
  const float* gamma_l = (const float*)d_in[14];
  const float* beta_l = (const float*)d_in[15];
  const float* Wout = (const float*)d_in[16];
  const float* bout = (const float*)d_in[17];
  float* out = (float*)d_out;

  char* w = (char*)d_ws;
  auto alloc = [&](size_t bytes) {
    void* p = (void*)w;
    w += (bytes + 255) & ~(size_t)255;
    return p;
  };
  // zero-initialized span: cnt | stAll | hp  (one memset)
  int* cnt = (int*)alloc((size_t)NN * 4);                      // 200192 rounded
  float* stAll = (float*)alloc((size_t)(4 * 256 + 2 * 512) * 4);  // 4 gcn-BN + 2 head-BN
  float* hp = (float*)alloc((size_t)GGv * GBv * 4);
  size_t zspan = (char*)w - (char*)cnt;
  // rest
  int* offs = (int*)alloc((size_t)(NN + 1) * 4);
  int* part = (int*)alloc((size_t)SCAN_BLOCKS * 4);
  int* cursor = (int*)alloc((size_t)NN * 4);
  int* col = (int*)alloc((size_t)EE * 4);
  float* dinv = (float*)alloc((size_t)NN * 4);
  ushort* hws = (ushort*)alloc((size_t)NN * GBv * 2);
  ushort* A = (ushort*)alloc((size_t)NN * GBv * 2);
  ushort* Wt0 = (ushort*)alloc((size_t)DINv * GBv * 2);
  ushort* Wtg = (ushort*)alloc((size_t)GDv * GBv * GBv * 2);
  float* m1 = (float*)alloc((size_t)GGv * LBv * 4);
  float* m2 = (float*)alloc((size_t)GGv * LBv * 4);

  float* stg0 = stAll;             // layer BN stats: 4 x 256 floats
  float* sth0 = stAll + 4 * 256;   // head BN stats: 2 x 512 floats
  float* sth1 = sth0 + 512;

  hipMemsetAsync(cnt, 0, zspan, stream);

  // degree + CSR
  k_hist<<<1024, 256, 0, stream>>>(ei + EE, cnt);
  k_dinv<<<(NN + 255) / 256, 256, 0, stream>>>(cnt, dinv);
  k_scan1<<<SCAN_BLOCKS, 256, 0, stream>>>(cnt, offs, part);
  k_scan2<<<1, 256, 0, stream>>>(part);
  k_scan3<<<SCAN_BLOCKS, 256, 0, stream>>>(offs, part);
  hipMemcpyAsync(cursor, offs, (size_t)NN * 4, hipMemcpyDeviceToDevice, stream);
  k_build<<<1024, 256, 0, stream>>>(ei, cursor, col);
  k_convW<<<(DINv * GBv + GDv * GBv * GBv + 255) / 256, 256, 0, stream>>>(W0, Wg, Wt0, Wtg);

  const int MMG = (NN + 63) / 64;  // 782

  // layer 0: h0 = relu(gcn(x, W0, b0))  -> stored f16 in A
  k_mm<DINv, 0><<<MMG, 256, 0, stream>>>(x, Wt0, nullptr, nullptr, nullptr, 0.f, dinv, hws);
  k_aggregate<true><<<NN / 4, 256, 0, stream>>>((const ushort2*)hws, col, offs, dinv, b0,
                                                (ushort2*)A);

  // layers 1..4
  for (int i = 0; i < GDv; i++) {
    if (i == 0)
      k_mm<GBv, 1><<<MMG, 256, 0, stream>>>(A, Wtg, nullptr, nullptr, nullptr, 0.f, dinv, hws);
    else
      k_mm<GBv, 2><<<MMG, 256, 0, stream>>>(A, Wtg + (size_t)i * GBv * GBv,
                                            stg0 + (size_t)(i - 1) * 256,
                                            gamma_g + (size_t)(i - 1) * GBv,
                                            beta_g + (size_t)(i - 1) * GBv, 1.f / NN, dinv, hws);
    k_aggregate<false><<<NN / 4, 256, 0, stream>>>((const ushort2*)hws, col, offs, dinv,
                                                   bg + (size_t)i * GBv, (ushort2*)A);
    k_colstats_h<<<1024, 128, 0, stream>>>(A, stg0 + (size_t)i * 256);
  }

  // pool with final BN+relu fused
  k_pool_bn<<<2048, 256, 0, stream>>>(A, stg0 + 3 * 256, gamma_g + 3 * GBv, beta_g + 3 * GBv,
                                      batch, hp);

  // head: t1 = relu(hp@Wl0+bl0); z1 = t1@Wl0'; z2 = bnrelu(z1)@Wl1'; out = bnrelu(z2)@Wout
  k_fc<GBv, 0><<<GGv, 256, 0, stream>>>(hp, Wl0, bl0, nullptr, nullptr, nullptr, m1);
  k_fc<LBv, 1><<<GGv, 256, 0, stream>>>(m1, Wl, bl, nullptr, nullptr, nullptr, m2);
  k_colstats<<<256, LBv, 0, stream>>>(m2, GGv, sth0);
  k_fc<LBv, 2><<<GGv, 256, 0, stream>>>(m2, Wl + (size_t)LBv * LBv, bl + LBv, sth0,
                                        gamma_l, beta_l, m1);
  k_colstats<<<256, LBv, 0, stream>>>(m1, GGv, sth1);
  k_out<<<GGv / 4, 256, 0, stream>>>(m1, sth1, gamma_l + LBv, beta_l + LBv, Wout, bout, out);
}

// Round 5
// 567.655 us; speedup vs baseline: 2.0894x; 1.1939x over previous
//
#include <hip/hip_runtime.h>

#define NN 50000
#define EE 640000
#define DINv 64
#define GBv 128
#define GDv 4
#define LBv 256
#define LDv 2
#define GGv 1024

#define SCAN_BLOCKS ((NN + 255) / 256)  // 196

typedef _Float16 f16x8 __attribute__((ext_vector_type(8)));
typedef float f32x4 __attribute__((ext_vector_type(4)));

__device__ __forceinline__ float h2f(ushort u) {
  union { ushort u; _Float16 h; } x;
  x.u = u;
  return (float)x.h;
}
__device__ __forceinline__ ushort f2h(float f) {
  union { ushort u; _Float16 h; } x;
  x.h = (_Float16)f;
  return x.u;
}

// ---------------- degree / CSR build ----------------

__global__ void k_hist(const int* __restrict__ dst, int* __restrict__ cnt) {
  int i = blockIdx.x * blockDim.x + threadIdx.x;
  int stride = gridDim.x * blockDim.x;
  for (; i < EE; i += stride) atomicAdd(&cnt[dst[i]], 1);
}

// scan1 also emits dinv = rsqrt(deg+1)
__global__ __launch_bounds__(256) void k_scan1(const int* __restrict__ cnt,
                                               int* __restrict__ offs,
                                               int* __restrict__ part,
                                               float* __restrict__ dinv) {
  __shared__ int sh[256];
  int tid = threadIdx.x;
  int idx = blockIdx.x * 256 + tid;
  int v = (idx < NN) ? cnt[idx] : 0;
  if (idx < NN) dinv[idx] = rsqrtf((float)(v + 1));
  sh[tid] = v;
  __syncthreads();
  for (int off = 1; off < 256; off <<= 1) {
    int t = (tid >= off) ? sh[tid - off] : 0;
    __syncthreads();
    sh[tid] += t;
    __syncthreads();
  }
  if (idx < NN) offs[idx] = sh[tid] - v;
  if (tid == 255) part[blockIdx.x] = sh[255];
}

__global__ __launch_bounds__(256) void k_scan2(int* __restrict__ part) {
  __shared__ int sh[256];
  int tid = threadIdx.x;
  int v = (tid < SCAN_BLOCKS) ? part[tid] : 0;
  sh[tid] = v;
  __syncthreads();
  for (int off = 1; off < 256; off <<= 1) {
    int t = (tid >= off) ? sh[tid - off] : 0;
    __syncthreads();
    sh[tid] += t;
    __syncthreads();
  }
  if (tid < SCAN_BLOCKS) part[tid] = sh[tid] - v;
}

// scan3 also writes cursor (saves a d2d memcpy dispatch)
__global__ __launch_bounds__(256) void k_scan3(int* __restrict__ offs,
                                               const int* __restrict__ part,
                                               int* __restrict__ cursor) {
  int idx = blockIdx.x * 256 + threadIdx.x;
  if (idx < NN) {
    int o = offs[idx] + part[blockIdx.x];
    offs[idx] = o;
    cursor[idx] = o;
  }
  if (idx == 0) offs[NN] = EE;
}

__global__ void k_build(const int* __restrict__ ei, int* __restrict__ cursor,
                        int* __restrict__ col) {
  int i = blockIdx.x * blockDim.x + threadIdx.x;
  int stride = gridDim.x * blockDim.x;
  for (; i < EE; i += stride) {
    int d = ei[EE + i];
    int p = atomicAdd(&cursor[d], 1);
    col[p] = ei[i];
  }
}

// ---------------- weight transpose+convert: Wt[c][k] = f16(W[k][c]) ----------------

__global__ void k_convW(const float* __restrict__ W0, const float* __restrict__ Wg,
                        ushort* __restrict__ Wt0, ushort* __restrict__ Wtg) {
  int idx = blockIdx.x * 256 + threadIdx.x;
  if (idx < DINv * GBv) {  // W0: [64][128] -> Wt0[c*64+k]
    int c = idx >> 6, k = idx & 63;
    Wt0[idx] = f2h(W0[k * GBv + c]);
  } else if (idx < DINv * GBv + GDv * GBv * GBv) {
    int e = idx - DINv * GBv;
    int i = e >> 14, rem = e & 16383;
    int c = rem >> 7, k = rem & 127;
    Wtg[e] = f2h(Wg[i * GBv * GBv + k * GBv + c]);
  }
}

// ---------------- u = x * dinv  (f16, 64-dim) ----------------

__global__ __launch_bounds__(256) void k_uprep(const float* __restrict__ x,
                                               const float* __restrict__ dinv,
                                               ushort* __restrict__ u) {
  int i = blockIdx.x * 256 + threadIdx.x;  // float4 index: NN*16 total
  if (i >= NN * 16) return;
  int n = i >> 4;
  float4 v = ((const float4*)x)[i];
  float d = dinv[n];
  union { ushort us[4]; uint2 q; } o;
  o.us[0] = f2h(v.x * d);
  o.us[1] = f2h(v.y * d);
  o.us[2] = f2h(v.z * d);
  o.us[3] = f2h(v.w * d);
  ((uint2*)u)[i] = o.q;
}

// ---------------- CSR aggregate (aggregate-first form) ----------------
// V[d] = f16( dinv[d] * ( row(d) + sum_src row(src) ) )
// row(s) = MODE0: U[s]  (already h*dinv)
//          MODE1: relu(G[s]) * dinv[s]
//          MODE2: relu(G[s]*S_c + T_c) * dinv[s]   (BN fold)
// 4 nodes/wave, 16 lanes/node, VEC halves per lane, unroll-4 edge loop.

template <int KH, int MODE>
__global__ __launch_bounds__(256) void k_agg(const ushort* __restrict__ G,
                                             const int* __restrict__ col,
                                             const int* __restrict__ offs,
                                             const float* __restrict__ dinv,
                                             const float* __restrict__ st,
                                             const float* __restrict__ gamma,
                                             const float* __restrict__ beta,
                                             ushort* __restrict__ V) {
  constexpr int VEC = KH / 16;  // halves per lane (8 or 4)
  __shared__ float sS[128], sT[128];
  int tid = threadIdx.x;
  if constexpr (MODE == 2) {
    if (tid < 128) {
      float mu = st[tid] * (1.f / NN);
      float var = st[128 + tid] * (1.f / NN) - mu * mu;
      float s = rsqrtf(var + 1e-5f) * gamma[tid];
      sS[tid] = s;
      sT[tid] = beta[tid] - mu * s;
    }
    __syncthreads();
  }
  int lane = tid & 63;
  int q = lane >> 4, m = lane & 15;
  int n = blockIdx.x * 16 + (tid >> 6) * 4 + q;  // 3125*16 = 50000 exact

  float sc[VEC], tc[VEC];
  if constexpr (MODE == 2) {
#pragma unroll
    for (int v = 0; v < VEC; v++) {
      sc[v] = sS[m * VEC + v];
      tc[v] = sT[m * VEC + v];
    }
  }

  union U { uint4 v4; uint2 v2; ushort us[8]; };
  auto loadrow = [&](int s) {
    U u;
    const ushort* p = G + (long)s * KH + m * VEC;
    if constexpr (VEC == 8) u.v4 = *(const uint4*)p;
    else u.v2 = *(const uint2*)p;
    return u;
  };
  float acc[VEC];
#pragma unroll
  for (int v = 0; v < VEC; v++) acc[v] = 0.f;
  auto addrow = [&](U u, float dv) {
#pragma unroll
    for (int v = 0; v < VEC; v++) {
      float g = h2f(u.us[v]);
      if constexpr (MODE == 0) acc[v] += g;
      else if constexpr (MODE == 1) acc[v] += fmaxf(g, 0.f) * dv;
      else acc[v] += fmaxf(g * sc[v] + tc[v], 0.f) * dv;
    }
  };

  float dn = dinv[n];
  addrow(loadrow(n), dn);  // self term

  int s0 = offs[n], s1 = offs[n + 1];
  int j = s0;
  for (; j + 3 < s1; j += 4) {
    int sa = col[j], sb = col[j + 1], s_c = col[j + 2], sd = col[j + 3];
    U ua = loadrow(sa), ub = loadrow(sb), uc = loadrow(s_c), ud = loadrow(sd);
    float da = 0.f, db = 0.f, dc = 0.f, dd = 0.f;
    if constexpr (MODE != 0) {
      da = dinv[sa]; db = dinv[sb]; dc = dinv[s_c]; dd = dinv[sd];
    }
    addrow(ua, da);
    addrow(ub, db);
    addrow(uc, dc);
    addrow(ud, dd);
  }
  for (; j < s1; j++) {
    int s = col[j];
    U u = loadrow(s);
    float dv = 0.f;
    if constexpr (MODE != 0) dv = dinv[s];
    addrow(u, dv);
  }

  U o;
#pragma unroll
  for (int v = 0; v < VEC; v++) o.us[v] = f2h(acc[v] * dn);
  ushort* op = V + (long)n * KH + m * VEC;
  if constexpr (VEC == 8) *(uint4*)op = o.v4;
  else *(uint2*)op = o.v2;
}

// ---------------- MFMA matmul: g[r][c] = f16( (V @ W)[r][c] + b[c] ) ----------------
// optional fused column stats (sum, sumsq of g) -> atomicAdd stG[0..128), stG[128..256)

template <int K, bool STATS>
__global__ __launch_bounds__(256) void k_mm(const ushort* __restrict__ X,
                                            const ushort* __restrict__ Wt,
                                            const float* __restrict__ bias,
                                            float* __restrict__ stG,
                                            ushort* __restrict__ Gout) {
  __shared__ __attribute__((aligned(16))) _Float16 sW[128 * K];
  __shared__ __attribute__((aligned(16))) _Float16 sA[64 * K];
  __shared__ float sB[128];
  __shared__ float ssum[128], ssq[128];
  int tid = threadIdx.x;
  int row0 = blockIdx.x * 64;

  // stage W
  {
    const uint4* src = (const uint4*)Wt;
    uint4* dst = (uint4*)sW;
    int n4 = 128 * K / 8;
    for (int i = tid; i < n4; i += 256) dst[i] = src[i];
  }
  if (tid < 128) {
    sB[tid] = bias[tid];
    if constexpr (STATS) {
      ssum[tid] = 0.f;
      ssq[tid] = 0.f;
    }
  }
  // stage A tile (64 rows x K halves)
  {
    int r = tid >> 2, col0 = (tid & 3) * (K / 4);
    int gr = row0 + r;
    const uint4* p = (const uint4*)(X + (long)gr * K + col0);
#pragma unroll
    for (int ch = 0; ch < K / 32; ch++) {
      uint4 v = (gr < NN) ? p[ch] : make_uint4(0, 0, 0, 0);
      *(uint4*)&sA[r * K + col0 + ch * 8] = v;
    }
  }
  __syncthreads();

  int w = tid >> 6, lane = tid & 63;
  int m = lane & 15, quad = lane >> 4;
  f32x4 acc[8];
#pragma unroll
  for (int ct = 0; ct < 8; ct++) acc[ct] = (f32x4){0.f, 0.f, 0.f, 0.f};
  const _Float16* pa = &sA[(16 * w + m) * K + quad * 8];
#pragma unroll
  for (int ks = 0; ks < K; ks += 32) {
    f16x8 a = *(const f16x8*)(pa + ks);
#pragma unroll
    for (int ct = 0; ct < 8; ct++) {
      f16x8 b = *(const f16x8*)&sW[(ct * 16 + m) * K + ks + quad * 8];
      acc[ct] = __builtin_amdgcn_mfma_f32_16x16x32_f16(a, b, acc[ct], 0, 0, 0);
    }
  }
  int crow = 16 * w + quad * 4;

  // fused column stats from registers
  if constexpr (STATS) {
#pragma unroll
    for (int ct = 0; ct < 8; ct++) {
      int c = ct * 16 + m;
      float b = sB[c];
      float ps = 0.f, pq = 0.f;
#pragma unroll
      for (int r = 0; r < 4; r++) {
        if (row0 + crow + r < NN) {
          float g = acc[ct][r] + b;
          ps += g;
          pq += g * g;
        }
      }
      ps += __shfl_xor(ps, 16);
      pq += __shfl_xor(pq, 16);
      ps += __shfl_xor(ps, 32);
      pq += __shfl_xor(pq, 32);
      if (quad == 0) {
        atomicAdd(&ssum[c], ps);
        atomicAdd(&ssq[c], pq);
      }
    }
  }
  __syncthreads();  // all waves done reading sA/sW

  // C -> LDS with bias, f16
  _Float16* P = (K == 128) ? sA : sW;
#pragma unroll
  for (int ct = 0; ct < 8; ct++) {
    int c = ct * 16 + m;
    float b = sB[c];
#pragma unroll
    for (int r = 0; r < 4; r++) P[(crow + r) * 128 + c] = (_Float16)(acc[ct][r] + b);
  }
  __syncthreads();

  // coalesced store
  {
    int r = tid >> 2, col0 = (tid & 3) * 32;
    int gr = row0 + r;
    if (gr < NN) {
      const uint4* src = (const uint4*)&P[r * 128 + col0];
      uint4* dst = (uint4*)(Gout + (long)gr * 128 + col0);
#pragma unroll
      for (int ch = 0; ch < 4; ch++) dst[ch] = src[ch];
    }
  }
  if constexpr (STATS) {
    if (tid < 128) {
      atomicAdd(&stG[tid], ssum[tid]);
      atomicAdd(&stG[128 + tid], ssq[tid]);
    }
  }
}

// ---------------- pool with fused BN+relu ----------------

__global__ __launch_bounds__(256) void k_pool_bn(const ushort* __restrict__ G,
                                                 const float* __restrict__ st,
                                                 const float* __restrict__ gamma,
                                                 const float* __restrict__ beta,
                                                 const int* __restrict__ batch,
                                                 float* __restrict__ hp) {
  __shared__ float sS[128], sT[128];
  if (threadIdx.x < 128) {
    int c = threadIdx.x;
    float m = st[c] * (1.f / NN);
    float v = st[128 + c] * (1.f / NN) - m * m;
    float s = rsqrtf(v + 1e-5f) * gamma[c];
    sS[c] = s;
    sT[c] = beta[c] - m * s;
  }
  __syncthreads();
  int i = blockIdx.x * 256 + threadIdx.x;
  int stride = gridDim.x * 256;
  for (; i < NN * 128; i += stride) {
    int n = i >> 7, c = i & 127;
    float y = fmaxf(h2f(G[i]) * sS[c] + sT[c], 0.f);
    atomicAdd(&hp[(long)batch[n] * 128 + c], y);
  }
}

// ---------------- head column stats (fp32) ----------------

__global__ void k_colstats(const float* __restrict__ X, int rows, float* __restrict__ st) {
  int c = threadIdx.x;
  int C = blockDim.x;
  float s = 0.f, q = 0.f;
  for (int r = blockIdx.x; r < rows; r += gridDim.x) {
    float v = X[(long)r * C + c];
    s += v;
    q += v * v;
  }
  atomicAdd(&st[c], s);
  atomicAdd(&st[C + c], q);
}

// ---------------- MLP head ----------------
// MODE 0: plain in + relu out; 1: plain in, no relu; 2: BN+relu on in, no relu out

template <int KIN, int MODE>
__global__ __launch_bounds__(256) void k_fc(const float* __restrict__ X,
                                            const float* __restrict__ W,
                                            const float* __restrict__ b,
                                            const float* __restrict__ st,
                                            const float* __restrict__ gamma,
                                            const float* __restrict__ beta,
                                            float* __restrict__ Y) {
  __shared__ float sx[KIN];
  int g = blockIdx.x;
  int c = threadIdx.x;
  for (int k = c; k < KIN; k += 256) {
    float v = X[(long)g * KIN + k];
    if constexpr (MODE == 2) {
      float m = st[k] * (1.f / GGv);
      float var = st[KIN + k] * (1.f / GGv) - m * m;
      v = fmaxf((v - m) * rsqrtf(var + 1e-5f) * gamma[k] + beta[k], 0.f);
    }
    sx[k] = v;
  }
  __syncthreads();
  float acc = b[c];
#pragma unroll 8
  for (int k = 0; k < KIN; k++) acc += sx[k] * W[(long)k * 256 + c];
  Y[(long)g * 256 + c] = (MODE == 0) ? fmaxf(acc, 0.f) : acc;
}

__global__ __launch_bounds__(256) void k_out(const float* __restrict__ X,
                                             const float* __restrict__ st,
                                             const float* __restrict__ gamma,
                                             const float* __restrict__ beta,
                                             const float* __restrict__ Wout,
                                             const float* __restrict__ bout,
                                             float* __restrict__ out) {
  int g = blockIdx.x * 4 + (threadIdx.x >> 6);
  int l = threadIdx.x & 63;
  float a0 = 0.f, a1 = 0.f;
  for (int k = l; k < LBv; k += 64) {
    float z = X[(long)g * LBv + k];
    float m = st[k] * (1.f / GGv);
    float var = st[LBv + k] * (1.f / GGv) - m * m;
    float x = fmaxf((z - m) * rsqrtf(var + 1e-5f) * gamma[k] + beta[k], 0.f);
    a0 += x * Wout[2 * k];
    a1 += x * Wout[2 * k + 1];
  }
  for (int off = 32; off > 0; off >>= 1) {
    a0 += __shfl_down(a0, off);
    a1 += __shfl_down(a1, off);
  }
  if (l == 0) {
    out[2 * g] = a0 + bout[0];
    out[2 * g + 1] = a1 + bout[1];
  }
}

// ---------------- launch ----------------

extern "C" void kernel_launch(void* const* d_in, const int* in_sizes, int n_in,
                              void* d_out, int out_size, void* d_ws, size_t ws_size,
                              hipStream_t stream) {
  const float* x = (const float*)d_in[0];
  const int* ei = (const int*)d_in[1];
  const int* batch = (const int*)d_in[2];
  const float* W0 = (const float*)d_in[4];
  const float* b0 = (const float*)d_in[5];
  const float* Wg = (const float*)d_in[6];
  const float* bg = (const float*)d_in[7];
  const float* gamma_g = (const float*)d_in[8];
  const float* beta_g = (const float*)d_in[9];
  const float* Wl0 = (const float*)d_in[10];
  const float* bl0 = (const float*)d_in[11];
  const float* Wl = (const float*)d_in[12];
  const float* bl = (const float*)d_in[13];
  const float* gamma_l = (const float*)d_in[14];
  const float* beta_l = (const float*)d_in[15];
  const float* Wout = (const float*)d_in[16];
  const float* bout = (const float*)d_in[17];
  float* out = (float*)d_out;

  char* w = (char*)d_ws;
  auto alloc = [&](size_t bytes) {
    void* p = (void*)w;
    w += (bytes + 255) & ~(size_t)255;
    return p;
  };
  // zero-initialized span: cnt | stAll | hp  (one memset per call)
  int* cnt = (int*)alloc((size_t)NN * 4);
  float* stAll = (float*)alloc((size_t)(4 * 256 + 2 * 512) * 4);
  float* hp = (float*)alloc((size_t)GGv * GBv * 4);
  size_t zspan = (char*)w - (char*)cnt;
  // rest
  int* offs = (int*)alloc((size_t)(NN + 1) * 4);
  int* part = (int*)alloc((size_t)SCAN_BLOCKS * 4);
  int* cursor = (int*)alloc((size_t)NN * 4);
  int* col = (int*)alloc((size_t)EE * 4);
  float* dinv = (float*)alloc((size_t)NN * 4);
  ushort* u = (ushort*)alloc((size_t)NN * DINv * 2);
  ushort* V = (ushort*)alloc((size_t)NN * GBv * 2);
  ushort* g = (ushort*)alloc((size_t)NN * GBv * 2);
  ushort* Wt0 = (ushort*)alloc((size_t)DINv * GBv * 2);
  ushort* Wtg = (ushort*)alloc((size_t)GDv * GBv * GBv * 2);
  float* m1 = (float*)alloc((size_t)GGv * LBv * 4);
  float* m2 = (float*)alloc((size_t)GGv * LBv * 4);

  float* stg = stAll;              // 4 x 256: stats of g1..g4
  float* sth0 = stAll + 4 * 256;   // head BN stats
  float* sth1 = sth0 + 512;

  hipMemsetAsync(cnt, 0, zspan, stream);

  // degree + CSR
  k_hist<<<1024, 256, 0, stream>>>(ei + EE, cnt);
  k_scan1<<<SCAN_BLOCKS, 256, 0, stream>>>(cnt, offs, part, dinv);
  k_scan2<<<1, 256, 0, stream>>>(part);
  k_scan3<<<SCAN_BLOCKS, 256, 0, stream>>>(offs, part, cursor);
  k_build<<<1024, 256, 0, stream>>>(ei, cursor, col);
  k_convW<<<(DINv * GBv + GDv * GBv * GBv + 255) / 256, 256, 0, stream>>>(W0, Wg, Wt0, Wtg);
  k_uprep<<<(NN * 16 + 255) / 256, 256, 0, stream>>>(x, dinv, u);

  const int AGG = NN / 16;         // 3125
  const int MMG = (NN + 63) / 64;  // 782

  // layer 0
  k_agg<64, 0><<<AGG, 256, 0, stream>>>(u, col, offs, dinv, nullptr, nullptr, nullptr, V);
  k_mm<64, false><<<MMG, 256, 0, stream>>>(V, Wt0, b0, nullptr, g);  // g0

  // layer 1 (relu-only fold)
  k_agg<128, 1><<<AGG, 256, 0, stream>>>(g, col, offs, dinv, nullptr, nullptr, nullptr, V);
  k_mm<128, true><<<MMG, 256, 0, stream>>>(V, Wtg, bg, stg, g);  // g1, stats->stg[0]

  // layers 2..4 (BN+relu fold)
  for (int i = 1; i < GDv; i++) {
    k_agg<128, 2><<<AGG, 256, 0, stream>>>(g, col, offs, dinv, stg + (size_t)(i - 1) * 256,
                                           gamma_g + (size_t)(i - 1) * GBv,
                                           beta_g + (size_t)(i - 1) * GBv, V);
    k_mm<128, true><<<MMG, 256, 0, stream>>>(V, Wtg + (size_t)i * GBv * GBv,
                                             bg + (size_t)i * GBv, stg + (size_t)i * 256, g);
  }

  // pool with final BN+relu fused
  k_pool_bn<<<2048, 256, 0, stream>>>(g, stg + 3 * 256, gamma_g + 3 * GBv, beta_g + 3 * GBv,
                                      batch, hp);

  // head
  k_fc<GBv, 0><<<GGv, 256, 0, stream>>>(hp, Wl0, bl0, nullptr, nullptr, nullptr, m1);
  k_fc<LBv, 1><<<GGv, 256, 0, stream>>>(m1, Wl, bl, nullptr, nullptr, nullptr, m2);
  k_colstats<<<256, LBv, 0, stream>>>(m2, GGv, sth0);
  k_fc<LBv, 2><<<GGv, 256, 0, stream>>>(m2, Wl + (size_t)LBv * LBv, bl + LBv, sth0,
                                        gamma_l, beta_l, m1);
  k_colstats<<<256, LBv, 0, stream>>>(m1, GGv, sth1);
  k_out<<<GGv / 4, 256, 0, stream>>>(m1, sth1, gamma_l + LBv, beta_l + LBv, Wout, bout, out);
}

// Round 6
// 517.050 us; speedup vs baseline: 2.2939x; 1.0979x over previous
//
#include <hip/hip_runtime.h>

#define NN 50000
#define EE 640000
#define DINv 64
#define GBv 128
#define GDv 4
#define LBv 256
#define LDv 2
#define GGv 1024

#define NB 196       // coarse buckets (256 nodes each)
#define BCAP 4096    // bucket capacity (mean 3277, +14 sigma safe)
#define BTILE 4096   // edges per k_bucket block
#define NBT ((EE + BTILE - 1) / BTILE)  // 157

typedef _Float16 f16x8 __attribute__((ext_vector_type(8)));
typedef float f32x4 __attribute__((ext_vector_type(4)));

__device__ __forceinline__ float h2f(ushort u) {
  union { ushort u; _Float16 h; } x;
  x.u = u;
  return (float)x.h;
}
__device__ __forceinline__ ushort f2h(float f) {
  union { ushort u; _Float16 h; } x;
  x.h = (_Float16)f;
  return x.u;
}

// ---------------- stage 1: coarse bucket sort (dst>>8), LDS-staged coalesced writes ----

__global__ __launch_bounds__(256) void k_bucket(const int* __restrict__ ei,
                                                int* __restrict__ bcnt,
                                                uint* __restrict__ bkt) {
  __shared__ int lcnt[NB];
  __shared__ int lbase[NB];
  __shared__ int gbase[NB];
  __shared__ int ls[256];
  __shared__ uint stage[BTILE];
  __shared__ ushort sb[BTILE];
  int tid = threadIdx.x;
  int t0 = blockIdx.x * BTILE;
  int cnt = min(BTILE, EE - t0);
  for (int i = tid; i < NB; i += 256) lcnt[i] = 0;
  __syncthreads();

  // pass 1: count + per-edge rank
  uint en[16];
  int bb[16], rk[16];
  int nper = (cnt + 255) >> 8;
  for (int k = 0; k < nper; k++) {
    int e = k * 256 + tid;
    if (e < cnt) {
      int src = ei[t0 + e];
      int dst = ei[EE + t0 + e];
      int b = dst >> 8;
      en[k] = ((uint)src << 8) | (uint)(dst & 255);
      bb[k] = b;
      rk[k] = atomicAdd(&lcnt[b], 1);
    } else {
      bb[k] = -1;
    }
  }
  __syncthreads();

  // scan lcnt -> lbase (exclusive); reserve global spans
  int v = (tid < NB) ? lcnt[tid] : 0;
  ls[tid] = v;
  __syncthreads();
  for (int off = 1; off < 256; off <<= 1) {
    int t = (tid >= off) ? ls[tid - off] : 0;
    __syncthreads();
    ls[tid] += t;
    __syncthreads();
  }
  if (tid < NB) {
    lbase[tid] = ls[tid] - v;
    gbase[tid] = atomicAdd(&bcnt[tid], v);
  }
  __syncthreads();

  // pass 2: stage bucket-grouped
  for (int k = 0; k < nper; k++) {
    if (bb[k] >= 0) {
      int slot = lbase[bb[k]] + rk[k];
      stage[slot] = en[k];
      sb[slot] = (ushort)bb[k];
    }
  }
  __syncthreads();

  // coalesced copy to global bucket spans
  for (int i = tid; i < cnt; i += 256) {
    int b = sb[i];
    bkt[(size_t)b * BCAP + gbase[b] + (i - lbase[b])] = stage[i];
  }
}

// exclusive scan of bcnt -> bbase; offs[NN] = EE
__global__ __launch_bounds__(256) void k_bscan(const int* __restrict__ bcnt,
                                               int* __restrict__ bbase,
                                               int* __restrict__ offs) {
  __shared__ int ls[256];
  int tid = threadIdx.x;
  int v = (tid < NB) ? bcnt[tid] : 0;
  ls[tid] = v;
  __syncthreads();
  for (int off = 1; off < 256; off <<= 1) {
    int t = (tid >= off) ? ls[tid - off] : 0;
    __syncthreads();
    ls[tid] += t;
    __syncthreads();
  }
  if (tid < NB) bbase[tid] = ls[tid] - v;
  if (tid == 0) offs[NN] = EE;
}

// ---------------- stage 2: per-bucket fine CSR + deg/dinv/offs ----------------

__global__ __launch_bounds__(256) void k_csr(const uint* __restrict__ bkt,
                                             const int* __restrict__ bcnt,
                                             const int* __restrict__ bbase,
                                             int* __restrict__ offs,
                                             float* __restrict__ dinv,
                                             int* __restrict__ col) {
  __shared__ int lhist[256];
  __shared__ int lofs[256];
  __shared__ int lcur[256];
  int b = blockIdx.x;
  int cnt = bcnt[b], base = bbase[b];
  const uint* B = bkt + (size_t)b * BCAP;
  int tid = threadIdx.x;
  lhist[tid] = 0;
  __syncthreads();
  for (int i = tid; i < cnt; i += 256) atomicAdd(&lhist[B[i] & 255], 1);
  __syncthreads();
  int v = lhist[tid];
  lofs[tid] = v;
  __syncthreads();
  for (int off = 1; off < 256; off <<= 1) {
    int t = (tid >= off) ? lofs[tid - off] : 0;
    __syncthreads();
    lofs[tid] += t;
    __syncthreads();
  }
  int excl = lofs[tid] - v;
  int n = b * 256 + tid;
  if (n < NN) {
    offs[n] = base + excl;
    dinv[n] = rsqrtf((float)(v + 1));
  }
  lcur[tid] = excl;
  __syncthreads();
  for (int i = tid; i < cnt; i += 256) {
    uint e = B[i];
    int p = atomicAdd(&lcur[e & 255], 1);
    col[base + p] = (int)(e >> 8);
  }
}

// ---------------- weight transpose+convert: Wt[c][k] = f16(W[k][c]) ----------------

__global__ void k_convW(const float* __restrict__ W0, const float* __restrict__ Wg,
                        ushort* __restrict__ Wt0, ushort* __restrict__ Wtg) {
  int idx = blockIdx.x * 256 + threadIdx.x;
  if (idx < DINv * GBv) {
    int c = idx >> 6, k = idx & 63;
    Wt0[idx] = f2h(W0[k * GBv + c]);
  } else if (idx < DINv * GBv + GDv * GBv * GBv) {
    int e = idx - DINv * GBv;
    int i = e >> 14, rem = e & 16383;
    int c = rem >> 7, k = rem & 127;
    Wtg[e] = f2h(Wg[i * GBv * GBv + k * GBv + c]);
  }
}

// ---------------- u = x * dinv  (f16, 64-dim) ----------------

__global__ __launch_bounds__(256) void k_uprep(const float* __restrict__ x,
                                               const float* __restrict__ dinv,
                                               ushort* __restrict__ u) {
  int i = blockIdx.x * 256 + threadIdx.x;
  if (i >= NN * 16) return;
  int n = i >> 4;
  float4 v = ((const float4*)x)[i];
  float d = dinv[n];
  union { ushort us[4]; uint2 q; } o;
  o.us[0] = f2h(v.x * d);
  o.us[1] = f2h(v.y * d);
  o.us[2] = f2h(v.z * d);
  o.us[3] = f2h(v.w * d);
  ((uint2*)u)[i] = o.q;
}

// ---------------- CSR aggregate (aggregate-first form) ----------------
// V[d] = f16( dinv[d] * ( row(d) + sum_src row(src) ) )
// MODE0: row=U[s]; MODE1: row=relu(G[s])*dinv[s]; MODE2: row=relu(G[s]*S+T)*dinv[s]

template <int KH, int MODE>
__global__ __launch_bounds__(256) void k_agg(const ushort* __restrict__ G,
                                             const int* __restrict__ col,
                                             const int* __restrict__ offs,
                                             const float* __restrict__ dinv,
                                             const float* __restrict__ st,
                                             const float* __restrict__ gamma,
                                             const float* __restrict__ beta,
                                             ushort* __restrict__ V) {
  constexpr int VEC = KH / 16;
  __shared__ float sS[128], sT[128];
  int tid = threadIdx.x;
  if constexpr (MODE == 2) {
    if (tid < 128) {
      float mu = st[tid] * (1.f / NN);
      float var = st[128 + tid] * (1.f / NN) - mu * mu;
      float s = rsqrtf(var + 1e-5f) * gamma[tid];
      sS[tid] = s;
      sT[tid] = beta[tid] - mu * s;
    }
    __syncthreads();
  }
  int lane = tid & 63;
  int q = lane >> 4, m = lane & 15;
  int n = blockIdx.x * 16 + (tid >> 6) * 4 + q;

  float sc[VEC], tc[VEC];
  if constexpr (MODE == 2) {
#pragma unroll
    for (int v = 0; v < VEC; v++) {
      sc[v] = sS[m * VEC + v];
      tc[v] = sT[m * VEC + v];
    }
  }

  union U { uint4 v4; uint2 v2; ushort us[8]; };
  auto loadrow = [&](int s) {
    U u;
    const ushort* p = G + (long)s * KH + m * VEC;
    if constexpr (VEC == 8) u.v4 = *(const uint4*)p;
    else u.v2 = *(const uint2*)p;
    return u;
  };
  float acc[VEC];
#pragma unroll
  for (int v = 0; v < VEC; v++) acc[v] = 0.f;
  auto addrow = [&](U u, float dv) {
#pragma unroll
    for (int v = 0; v < VEC; v++) {
      float g = h2f(u.us[v]);
      if constexpr (MODE == 0) acc[v] += g;
      else if constexpr (MODE == 1) acc[v] += fmaxf(g, 0.f) * dv;
      else acc[v] += fmaxf(g * sc[v] + tc[v], 0.f) * dv;
    }
  };

  float dn = dinv[n];
  addrow(loadrow(n), dn);

  int s0 = offs[n], s1 = offs[n + 1];
  int j = s0;
  for (; j + 7 < s1; j += 8) {
    int si[8];
#pragma unroll
    for (int t = 0; t < 8; t++) si[t] = col[j + t];
    U uu[8];
#pragma unroll
    for (int t = 0; t < 8; t++) uu[t] = loadrow(si[t]);
    float dd[8];
#pragma unroll
    for (int t = 0; t < 8; t++) dd[t] = (MODE != 0) ? dinv[si[t]] : 0.f;
#pragma unroll
    for (int t = 0; t < 8; t++) addrow(uu[t], dd[t]);
  }
  for (; j + 3 < s1; j += 4) {
    int si[4];
#pragma unroll
    for (int t = 0; t < 4; t++) si[t] = col[j + t];
    U uu[4];
#pragma unroll
    for (int t = 0; t < 4; t++) uu[t] = loadrow(si[t]);
    float dd[4];
#pragma unroll
    for (int t = 0; t < 4; t++) dd[t] = (MODE != 0) ? dinv[si[t]] : 0.f;
#pragma unroll
    for (int t = 0; t < 4; t++) addrow(uu[t], dd[t]);
  }
  for (; j < s1; j++) {
    int s = col[j];
    U u = loadrow(s);
    float dv = (MODE != 0) ? dinv[s] : 0.f;
    addrow(u, dv);
  }

  U o;
#pragma unroll
  for (int v = 0; v < VEC; v++) o.us[v] = f2h(acc[v] * dn);
  ushort* op = V + (long)n * KH + m * VEC;
  if constexpr (VEC == 8) *(uint4*)op = o.v4;
  else *(uint2*)op = o.v2;
}

// ---------------- MFMA matmul: g[r][c] = f16( (V @ W)[r][c] + b[c] ), fused stats ----

template <int K, bool STATS>
__global__ __launch_bounds__(256) void k_mm(const ushort* __restrict__ X,
                                            const ushort* __restrict__ Wt,
                                            const float* __restrict__ bias,
                                            float* __restrict__ stG,
                                            ushort* __restrict__ Gout) {
  __shared__ __attribute__((aligned(16))) _Float16 sW[128 * K];
  __shared__ __attribute__((aligned(16))) _Float16 sA[64 * K];
  __shared__ float sB[128];
  __shared__ float ssum[128], ssq[128];
  int tid = threadIdx.x;
  int row0 = blockIdx.x * 64;

  {
    const uint4* src = (const uint4*)Wt;
    uint4* dst = (uint4*)sW;
    int n4 = 128 * K / 8;
    for (int i = tid; i < n4; i += 256) dst[i] = src[i];
  }
  if (tid < 128) {
    sB[tid] = bias[tid];
    if constexpr (STATS) {
      ssum[tid] = 0.f;
      ssq[tid] = 0.f;
    }
  }
  {
    int r = tid >> 2, col0 = (tid & 3) * (K / 4);
    int gr = row0 + r;
    const uint4* p = (const uint4*)(X + (long)gr * K + col0);
#pragma unroll
    for (int ch = 0; ch < K / 32; ch++) {
      uint4 v = (gr < NN) ? p[ch] : make_uint4(0, 0, 0, 0);
      *(uint4*)&sA[r * K + col0 + ch * 8] = v;
    }
  }
  __syncthreads();

  int w = tid >> 6, lane = tid & 63;
  int m = lane & 15, quad = lane >> 4;
  f32x4 acc[8];
#pragma unroll
  for (int ct = 0; ct < 8; ct++) acc[ct] = (f32x4){0.f, 0.f, 0.f, 0.f};
  const _Float16* pa = &sA[(16 * w + m) * K + quad * 8];
#pragma unroll
  for (int ks = 0; ks < K; ks += 32) {
    f16x8 a = *(const f16x8*)(pa + ks);
#pragma unroll
    for (int ct = 0; ct < 8; ct++) {
      f16x8 b = *(const f16x8*)&sW[(ct * 16 + m) * K + ks + quad * 8];
      acc[ct] = __builtin_amdgcn_mfma_f32_16x16x32_f16(a, b, acc[ct], 0, 0, 0);
    }
  }
  int crow = 16 * w + quad * 4;

  if constexpr (STATS) {
#pragma unroll
    for (int ct = 0; ct < 8; ct++) {
      int c = ct * 16 + m;
      float b = sB[c];
      float ps = 0.f, pq = 0.f;
#pragma unroll
      for (int r = 0; r < 4; r++) {
        if (row0 + crow + r < NN) {
          float g = acc[ct][r] + b;
          ps += g;
          pq += g * g;
        }
      }
      ps += __shfl_xor(ps, 16);
      pq += __shfl_xor(pq, 16);
      ps += __shfl_xor(ps, 32);
      pq += __shfl_xor(pq, 32);
      if (quad == 0) {
        atomicAdd(&ssum[c], ps);
        atomicAdd(&ssq[c], pq);
      }
    }
  }
  __syncthreads();

  _Float16* P = (K == 128) ? sA : sW;
#pragma unroll
  for (int ct = 0; ct < 8; ct++) {
    int c = ct * 16 + m;
    float b = sB[c];
#pragma unroll
    for (int r = 0; r < 4; r++) P[(crow + r) * 128 + c] = (_Float16)(acc[ct][r] + b);
  }
  __syncthreads();

  {
    int r = tid >> 2, col0 = (tid & 3) * 32;
    int gr = row0 + r;
    if (gr < NN) {
      const uint4* src = (const uint4*)&P[r * 128 + col0];
      uint4* dst = (uint4*)(Gout + (long)gr * 128 + col0);
#pragma unroll
      for (int ch = 0; ch < 4; ch++) dst[ch] = src[ch];
    }
  }
  if constexpr (STATS) {
    if (tid < 128) {
      atomicAdd(&stG[tid], ssum[tid]);
      atomicAdd(&stG[128 + tid], ssq[tid]);
    }
  }
}

// ---------------- pool: per-graph segmented reduction (batch sorted, no atomics) ----

__global__ __launch_bounds__(128) void k_pool2(const ushort* __restrict__ G,
                                               const float* __restrict__ st,
                                               const float* __restrict__ gamma,
                                               const float* __restrict__ beta,
                                               const int* __restrict__ batch,
                                               float* __restrict__ hp) {
  __shared__ int sse[2];
  int g = blockIdx.x;
  int c = threadIdx.x;
  if (c < 2) {
    int key = g + c;
    int lo = 0, hi = NN;
    while (lo < hi) {
      int mid = (lo + hi) >> 1;
      if (batch[mid] < key) lo = mid + 1;
      else hi = mid;
    }
    sse[c] = lo;
  }
  __syncthreads();
  int s = sse[0], e = sse[1];
  float m = st[c] * (1.f / NN);
  float v = st[128 + c] * (1.f / NN) - m * m;
  float sc = rsqrtf(v + 1e-5f) * gamma[c];
  float tc = beta[c] - m * sc;
  float acc = 0.f;
  for (int n = s; n < e; n++) acc += fmaxf(h2f(G[(long)n * 128 + c]) * sc + tc, 0.f);
  hp[(long)g * 128 + c] = acc;
}

// ---------------- head column stats (fp32) ----------------

__global__ void k_colstats(const float* __restrict__ X, int rows, float* __restrict__ st) {
  int c = threadIdx.x;
  int C = blockDim.x;
  float s = 0.f, q = 0.f;
  for (int r = blockIdx.x; r < rows; r += gridDim.x) {
    float v = X[(long)r * C + c];
    s += v;
    q += v * v;
  }
  atomicAdd(&st[c], s);
  atomicAdd(&st[C + c], q);
}

// ---------------- MLP head ----------------
// MODE 0: plain in + relu out; 1: plain in, no relu; 2: BN+relu on in, no relu out

template <int KIN, int MODE>
__global__ __launch_bounds__(256) void k_fc(const float* __restrict__ X,
                                            const float* __restrict__ W,
                                            const float* __restrict__ b,
                                            const float* __restrict__ st,
                                            const float* __restrict__ gamma,
                                            const float* __restrict__ beta,
                                            float* __restrict__ Y) {
  __shared__ float sx[KIN];
  int g = blockIdx.x;
  int c = threadIdx.x;
  for (int k = c; k < KIN; k += 256) {
    float v = X[(long)g * KIN + k];
    if constexpr (MODE == 2) {
      float m = st[k] * (1.f / GGv);
      float var = st[KIN + k] * (1.f / GGv) - m * m;
      v = fmaxf((v - m) * rsqrtf(var + 1e-5f) * gamma[k] + beta[k], 0.f);
    }
    sx[k] = v;
  }
  __syncthreads();
  float acc = b[c];
#pragma unroll 8
  for (int k = 0; k < KIN; k++) acc += sx[k] * W[(long)k * 256 + c];
  Y[(long)g * 256 + c] = (MODE == 0) ? fmaxf(acc, 0.f) : acc;
}

__global__ __launch_bounds__(256) void k_out(const float* __restrict__ X,
                                             const float* __restrict__ st,
                                             const float* __restrict__ gamma,
                                             const float* __restrict__ beta,
                                             const float* __restrict__ Wout,
                                             const float* __restrict__ bout,
                                             float* __restrict__ out) {
  int g = blockIdx.x * 4 + (threadIdx.x >> 6);
  int l = threadIdx.x & 63;
  float a0 = 0.f, a1 = 0.f;
  for (int k = l; k < LBv; k += 64) {
    float z = X[(long)g * LBv + k];
    float m = st[k] * (1.f / GGv);
    float var = st[LBv + k] * (1.f / GGv) - m * m;
    float x = fmaxf((z - m) * rsqrtf(var + 1e-5f) * gamma[k] + beta[k], 0.f);
    a0 += x * Wout[2 * k];
    a1 += x * Wout[2 * k + 1];
  }
  for (int off = 32; off > 0; off >>= 1) {
    a0 += __shfl_down(a0, off);
    a1 += __shfl_down(a1, off);
  }
  if (l == 0) {
    out[2 * g] = a0 + bout[0];
    out[2 * g + 1] = a1 + bout[1];
  }
}

// ---------------- launch ----------------

extern "C" void kernel_launch(void* const* d_in, const int* in_sizes, int n_in,
                              void* d_out, int out_size, void* d_ws, size_t ws_size,
                              hipStream_t stream) {
  const float* x = (const float*)d_in[0];
  const int* ei = (const int*)d_in[1];
  const int* batch = (const int*)d_in[2];
  const float* W0 = (const float*)d_in[4];
  const float* b0 = (const float*)d_in[5];
  const float* Wg = (const float*)d_in[6];
  const float* bg = (const float*)d_in[7];
  const float* gamma_g = (const float*)d_in[8];
  const float* beta_g = (const float*)d_in[9];
  const float* Wl0 = (const float*)d_in[10];
  const float* bl0 = (const float*)d_in[11];
  const float* Wl = (const float*)d_in[12];
  const float* bl = (const float*)d_in[13];
  const float* gamma_l = (const float*)d_in[14];
  const float* beta_l = (const float*)d_in[15];
  const float* Wout = (const float*)d_in[16];
  const float* bout = (const float*)d_in[17];
  float* out = (float*)d_out;

  char* w = (char*)d_ws;
  auto alloc = [&](size_t bytes) {
    void* p = (void*)w;
    w += (bytes + 255) & ~(size_t)255;
    return p;
  };
  // zero-initialized span: bcnt | stAll  (one small memset per call)
  int* bcnt = (int*)alloc((size_t)NB * 4);
  float* stAll = (float*)alloc((size_t)(4 * 256 + 2 * 512) * 4);
  size_t zspan = (char*)w - (char*)bcnt;
  // rest
  uint* bkt = (uint*)alloc((size_t)NB * BCAP * 4);
  int* bbase = (int*)alloc((size_t)NB * 4);
  int* offs = (int*)alloc((size_t)(NN + 1) * 4);
  int* col = (int*)alloc((size_t)EE * 4);
  float* dinv = (float*)alloc((size_t)NN * 4);
  ushort* u = (ushort*)alloc((size_t)NN * DINv * 2);
  ushort* V = (ushort*)alloc((size_t)NN * GBv * 2);
  ushort* g = (ushort*)alloc((size_t)NN * GBv * 2);
  ushort* Wt0 = (ushort*)alloc((size_t)DINv * GBv * 2);
  ushort* Wtg = (ushort*)alloc((size_t)GDv * GBv * GBv * 2);
  float* hp = (float*)alloc((size_t)GGv * GBv * 4);
  float* m1 = (float*)alloc((size_t)GGv * LBv * 4);
  float* m2 = (float*)alloc((size_t)GGv * LBv * 4);

  float* stg = stAll;
  float* sth0 = stAll + 4 * 256;
  float* sth1 = sth0 + 512;

  hipMemsetAsync(bcnt, 0, zspan, stream);

  // CSR: bucket sort -> bucket scan -> per-bucket fine CSR (+deg/dinv/offs)
  k_bucket<<<NBT, 256, 0, stream>>>(ei, bcnt, bkt);
  k_bscan<<<1, 256, 0, stream>>>(bcnt, bbase, offs);
  k_csr<<<NB, 256, 0, stream>>>(bkt, bcnt, bbase, offs, dinv, col);
  k_convW<<<(DINv * GBv + GDv * GBv * GBv + 255) / 256, 256, 0, stream>>>(W0, Wg, Wt0, Wtg);
  k_uprep<<<(NN * 16 + 255) / 256, 256, 0, stream>>>(x, dinv, u);

  const int AGG = NN / 16;         // 3125
  const int MMG = (NN + 63) / 64;  // 782

  // layer 0
  k_agg<64, 0><<<AGG, 256, 0, stream>>>(u, col, offs, dinv, nullptr, nullptr, nullptr, V);
  k_mm<64, false><<<MMG, 256, 0, stream>>>(V, Wt0, b0, nullptr, g);

  // layer 1 (relu fold)
  k_agg<128, 1><<<AGG, 256, 0, stream>>>(g, col, offs, dinv, nullptr, nullptr, nullptr, V);
  k_mm<128, true><<<MMG, 256, 0, stream>>>(V, Wtg, bg, stg, g);

  // layers 2..4 (BN+relu fold)
  for (int i = 1; i < GDv; i++) {
    k_agg<128, 2><<<AGG, 256, 0, stream>>>(g, col, offs, dinv, stg + (size_t)(i - 1) * 256,
                                           gamma_g + (size_t)(i - 1) * GBv,
                                           beta_g + (size_t)(i - 1) * GBv, V);
    k_mm<128, true><<<MMG, 256, 0, stream>>>(V, Wtg + (size_t)i * GBv * GBv,
                                             bg + (size_t)i * GBv, stg + (size_t)i * 256, g);
  }

  // pool with final BN+relu fused (segmented, no atomics)
  k_pool2<<<GGv, 128, 0, stream>>>(g, stg + 3 * 256, gamma_g + 3 * GBv, beta_g + 3 * GBv,
                                   batch, hp);

  // head
  k_fc<GBv, 0><<<GGv, 256, 0, stream>>>(hp, Wl0, bl0, nullptr, nullptr, nullptr, m1);
  k_fc<LBv, 1><<<GGv, 256, 0, stream>>>(m1, Wl, bl, nullptr, nullptr, nullptr, m2);
  k_colstats<<<256, LBv, 0, stream>>>(m2, GGv, sth0);
  k_fc<LBv, 2><<<GGv, 256, 0, stream>>>(m2, Wl + (size_t)LBv * LBv, bl + LBv, sth0,
                                        gamma_l, beta_l, m1);
  k_colstats<<<256, LBv, 0, stream>>>(m1, GGv, sth1);
  k_out<<<GGv / 4, 256, 0, stream>>>(m1, sth1, gamma_l + LBv, beta_l + LBv, Wout, bout, out);
}

// Round 7
// 451.801 us; speedup vs baseline: 2.6251x; 1.1444x over previous
//
#include <hip/hip_runtime.h>

#define NN 50000
#define EE 640000
#define DINv 64
#define GBv 128
#define GDv 4
#define LBv 256
#define LDv 2
#define GGv 1024

#define NB 196       // coarse buckets (256 nodes each)
#define BCAP 4096    // bucket capacity (mean 3277, +14 sigma safe)
#define BTILE 4096   // edges per k_bucket block
#define NBT ((EE + BTILE - 1) / BTILE)  // 157

#define NTILES ((NN + 63) / 64)  // 782 row-tiles for k_mm

typedef _Float16 f16x8 __attribute__((ext_vector_type(8)));
typedef float f32x4 __attribute__((ext_vector_type(4)));

__device__ __forceinline__ float h2f(ushort u) {
  union { ushort u; _Float16 h; } x;
  x.u = u;
  return (float)x.h;
}
__device__ __forceinline__ ushort f2h(float f) {
  union { ushort u; _Float16 h; } x;
  x.h = (_Float16)f;
  return x.u;
}

// ---------------- stage 1: coarse bucket sort (dst>>8), LDS-staged coalesced writes ----

__global__ __launch_bounds__(256) void k_bucket(const int* __restrict__ ei,
                                                int* __restrict__ bcnt,
                                                uint* __restrict__ bkt) {
  __shared__ int lcnt[NB];
  __shared__ int lbase[NB];
  __shared__ int gbase[NB];
  __shared__ int ls[256];
  __shared__ uint stage[BTILE];
  __shared__ ushort sb[BTILE];
  int tid = threadIdx.x;
  int t0 = blockIdx.x * BTILE;
  int cnt = min(BTILE, EE - t0);
  for (int i = tid; i < NB; i += 256) lcnt[i] = 0;
  __syncthreads();

  uint en[16];
  int bb[16], rk[16];
  int nper = (cnt + 255) >> 8;
  for (int k = 0; k < nper; k++) {
    int e = k * 256 + tid;
    if (e < cnt) {
      int src = ei[t0 + e];
      int dst = ei[EE + t0 + e];
      int b = dst >> 8;
      en[k] = ((uint)src << 8) | (uint)(dst & 255);
      bb[k] = b;
      rk[k] = atomicAdd(&lcnt[b], 1);
    } else {
      bb[k] = -1;
    }
  }
  __syncthreads();

  int v = (tid < NB) ? lcnt[tid] : 0;
  ls[tid] = v;
  __syncthreads();
  for (int off = 1; off < 256; off <<= 1) {
    int t = (tid >= off) ? ls[tid - off] : 0;
    __syncthreads();
    ls[tid] += t;
    __syncthreads();
  }
  if (tid < NB) {
    lbase[tid] = ls[tid] - v;
    gbase[tid] = atomicAdd(&bcnt[tid], v);
  }
  __syncthreads();

  for (int k = 0; k < nper; k++) {
    if (bb[k] >= 0) {
      int slot = lbase[bb[k]] + rk[k];
      stage[slot] = en[k];
      sb[slot] = (ushort)bb[k];
    }
  }
  __syncthreads();

  for (int i = tid; i < cnt; i += 256) {
    int b = sb[i];
    bkt[(size_t)b * BCAP + gbase[b] + (i - lbase[b])] = stage[i];
  }
}

__global__ __launch_bounds__(256) void k_bscan(const int* __restrict__ bcnt,
                                               int* __restrict__ bbase,
                                               int* __restrict__ offs) {
  __shared__ int ls[256];
  int tid = threadIdx.x;
  int v = (tid < NB) ? bcnt[tid] : 0;
  ls[tid] = v;
  __syncthreads();
  for (int off = 1; off < 256; off <<= 1) {
    int t = (tid >= off) ? ls[tid - off] : 0;
    __syncthreads();
    ls[tid] += t;
    __syncthreads();
  }
  if (tid < NB) bbase[tid] = ls[tid] - v;
  if (tid == 0) offs[NN] = EE;
}

// ---------------- stage 2: per-bucket fine CSR + deg/dinv/offs ----------------

__global__ __launch_bounds__(256) void k_csr(const uint* __restrict__ bkt,
                                             const int* __restrict__ bcnt,
                                             const int* __restrict__ bbase,
                                             int* __restrict__ offs,
                                             float* __restrict__ dinv,
                                             int* __restrict__ col) {
  __shared__ int lhist[256];
  __shared__ int lofs[256];
  __shared__ int lcur[256];
  int b = blockIdx.x;
  int cnt = bcnt[b], base = bbase[b];
  const uint* B = bkt + (size_t)b * BCAP;
  int tid = threadIdx.x;
  lhist[tid] = 0;
  __syncthreads();
  for (int i = tid; i < cnt; i += 256) atomicAdd(&lhist[B[i] & 255], 1);
  __syncthreads();
  int v = lhist[tid];
  lofs[tid] = v;
  __syncthreads();
  for (int off = 1; off < 256; off <<= 1) {
    int t = (tid >= off) ? lofs[tid - off] : 0;
    __syncthreads();
    lofs[tid] += t;
    __syncthreads();
  }
  int excl = lofs[tid] - v;
  int n = b * 256 + tid;
  if (n < NN) {
    offs[n] = base + excl;
    dinv[n] = rsqrtf((float)(v + 1));
  }
  lcur[tid] = excl;
  __syncthreads();
  for (int i = tid; i < cnt; i += 256) {
    uint e = B[i];
    int p = atomicAdd(&lcur[e & 255], 1);
    col[base + p] = (int)(e >> 8);
  }
}

// ---------------- weight transpose+convert: Wt[c][k] = f16(W[k][c]) ----------------

__global__ void k_convW(const float* __restrict__ W0, const float* __restrict__ Wg,
                        ushort* __restrict__ Wt0, ushort* __restrict__ Wtg) {
  int idx = blockIdx.x * 256 + threadIdx.x;
  if (idx < DINv * GBv) {
    int c = idx >> 6, k = idx & 63;
    Wt0[idx] = f2h(W0[k * GBv + c]);
  } else if (idx < DINv * GBv + GDv * GBv * GBv) {
    int e = idx - DINv * GBv;
    int i = e >> 14, rem = e & 16383;
    int c = rem >> 7, k = rem & 127;
    Wtg[e] = f2h(Wg[i * GBv * GBv + k * GBv + c]);
  }
}

// ---------------- u = x * dinv  (f16, 64-dim) ----------------

__global__ __launch_bounds__(256) void k_uprep(const float* __restrict__ x,
                                               const float* __restrict__ dinv,
                                               ushort* __restrict__ u) {
  int i = blockIdx.x * 256 + threadIdx.x;
  if (i >= NN * 16) return;
  int n = i >> 4;
  float4 v = ((const float4*)x)[i];
  float d = dinv[n];
  union { ushort us[4]; uint2 q; } o;
  o.us[0] = f2h(v.x * d);
  o.us[1] = f2h(v.y * d);
  o.us[2] = f2h(v.z * d);
  o.us[3] = f2h(v.w * d);
  ((uint2*)u)[i] = o.q;
}

// ---------------- CSR aggregate (aggregate-first form) ----------------

template <int KH, int MODE>
__global__ __launch_bounds__(256) void k_agg(const ushort* __restrict__ G,
                                             const int* __restrict__ col,
                                             const int* __restrict__ offs,
                                             const float* __restrict__ dinv,
                                             const float* __restrict__ st,
                                             const float* __restrict__ gamma,
                                             const float* __restrict__ beta,
                                             ushort* __restrict__ V) {
  constexpr int VEC = KH / 16;
  __shared__ float sS[128], sT[128];
  int tid = threadIdx.x;
  if constexpr (MODE == 2) {
    if (tid < 128) {
      float mu = st[tid] * (1.f / NN);
      float var = st[128 + tid] * (1.f / NN) - mu * mu;
      float s = rsqrtf(var + 1e-5f) * gamma[tid];
      sS[tid] = s;
      sT[tid] = beta[tid] - mu * s;
    }
    __syncthreads();
  }
  int lane = tid & 63;
  int q = lane >> 4, m = lane & 15;
  int n = blockIdx.x * 16 + (tid >> 6) * 4 + q;

  float sc[VEC], tc[VEC];
  if constexpr (MODE == 2) {
#pragma unroll
    for (int v = 0; v < VEC; v++) {
      sc[v] = sS[m * VEC + v];
      tc[v] = sT[m * VEC + v];
    }
  }

  union U { uint4 v4; uint2 v2; ushort us[8]; };
  auto loadrow = [&](int s) {
    U u;
    const ushort* p = G + (long)s * KH + m * VEC;
    if constexpr (VEC == 8) u.v4 = *(const uint4*)p;
    else u.v2 = *(const uint2*)p;
    return u;
  };
  float acc[VEC];
#pragma unroll
  for (int v = 0; v < VEC; v++) acc[v] = 0.f;
  auto addrow = [&](U u, float dv) {
#pragma unroll
    for (int v = 0; v < VEC; v++) {
      float g = h2f(u.us[v]);
      if constexpr (MODE == 0) acc[v] += g;
      else if constexpr (MODE == 1) acc[v] += fmaxf(g, 0.f) * dv;
      else acc[v] += fmaxf(g * sc[v] + tc[v], 0.f) * dv;
    }
  };

  float dn = dinv[n];
  addrow(loadrow(n), dn);

  int s0 = offs[n], s1 = offs[n + 1];
  int j = s0;
  for (; j + 7 < s1; j += 8) {
    int si[8];
#pragma unroll
    for (int t = 0; t < 8; t++) si[t] = col[j + t];
    U uu[8];
#pragma unroll
    for (int t = 0; t < 8; t++) uu[t] = loadrow(si[t]);
    float dd[8];
#pragma unroll
    for (int t = 0; t < 8; t++) dd[t] = (MODE != 0) ? dinv[si[t]] : 0.f;
#pragma unroll
    for (int t = 0; t < 8; t++) addrow(uu[t], dd[t]);
  }
  for (; j + 3 < s1; j += 4) {
    int si[4];
#pragma unroll
    for (int t = 0; t < 4; t++) si[t] = col[j + t];
    U uu[4];
#pragma unroll
    for (int t = 0; t < 4; t++) uu[t] = loadrow(si[t]);
    float dd[4];
#pragma unroll
    for (int t = 0; t < 4; t++) dd[t] = (MODE != 0) ? dinv[si[t]] : 0.f;
#pragma unroll
    for (int t = 0; t < 4; t++) addrow(uu[t], dd[t]);
  }
  for (; j < s1; j++) {
    int s = col[j];
    U u = loadrow(s);
    float dv = (MODE != 0) ? dinv[s] : 0.f;
    addrow(u, dv);
  }

  U o;
#pragma unroll
  for (int v = 0; v < VEC; v++) o.us[v] = f2h(acc[v] * dn);
  ushort* op = V + (long)n * KH + m * VEC;
  if constexpr (VEC == 8) *(uint4*)op = o.v4;
  else *(uint2*)op = o.v2;
}

// ---------------- MFMA matmul: g[r][c] = f16( (V @ W)[r][c] + b[c] ), fused stats ----
// Persistent-W grid-stride over 64-row tiles; padded LDS strides (bank-conflict-free);
// stats accumulated in registers across tiles, flushed once per block.

template <int K, bool STATS>
__global__ __launch_bounds__(256) void k_mm(const ushort* __restrict__ X,
                                            const ushort* __restrict__ Wt,
                                            const float* __restrict__ bias,
                                            float* __restrict__ stG,
                                            ushort* __restrict__ Gout) {
  constexpr int KP = K + 8;              // padded stride, halves (72 / 136)
  constexpr int CP = 136;                // C buffer stride
  constexpr bool REUSE = (K == 128);     // reuse sA as C buffer when it fits
  __shared__ __attribute__((aligned(16))) _Float16 sW[128 * KP];
  __shared__ __attribute__((aligned(16))) _Float16 sA[64 * KP];
  __shared__ __attribute__((aligned(16))) _Float16 sCbuf[REUSE ? 8 : 64 * CP];
  __shared__ float sB[128];
  __shared__ float ssum[128], ssq[128];
  _Float16* sC = REUSE ? sA : sCbuf;
  int tid = threadIdx.x;

  // stage W once per block (padded rows)
  {
    constexpr int CH = K / 8;  // uint4 chunks per row
    for (int i = tid; i < 128 * CH; i += 256) {
      int c = i / CH, ch = i - c * CH;
      *(uint4*)&sW[c * KP + ch * 8] = ((const uint4*)Wt)[i];
    }
  }
  if (tid < 128) {
    sB[tid] = bias[tid];
    if constexpr (STATS) {
      ssum[tid] = 0.f;
      ssq[tid] = 0.f;
    }
  }

  int w = tid >> 6, lane = tid & 63;
  int m = lane & 15, quad = lane >> 4;
  int crow = 16 * w + quad * 4;

  float ps[8], pq[8];
  if constexpr (STATS) {
#pragma unroll
    for (int ct = 0; ct < 8; ct++) { ps[ct] = 0.f; pq[ct] = 0.f; }
  }

  for (int tile = blockIdx.x; tile < NTILES; tile += gridDim.x) {
    int row0 = tile * 64;
    __syncthreads();  // prior iteration's sC reads / first-iter W stage

    // stage A tile (64 rows x K halves, padded stride)
    {
      int r = tid >> 2, col0 = (tid & 3) * (K / 4);
      int gr = row0 + r;
      const uint4* p = (const uint4*)(X + (long)gr * K + col0);
#pragma unroll
      for (int ch = 0; ch < K / 32; ch++) {
        uint4 v = (gr < NN) ? p[ch] : make_uint4(0, 0, 0, 0);
        *(uint4*)&sA[r * KP + col0 + ch * 8] = v;
      }
    }
    __syncthreads();

    f32x4 acc[8];
#pragma unroll
    for (int ct = 0; ct < 8; ct++) acc[ct] = (f32x4){0.f, 0.f, 0.f, 0.f};
    const _Float16* pa = &sA[(16 * w + m) * KP + quad * 8];
#pragma unroll
    for (int ks = 0; ks < K; ks += 32) {
      f16x8 a = *(const f16x8*)(pa + ks);
#pragma unroll
      for (int ct = 0; ct < 8; ct++) {
        f16x8 b = *(const f16x8*)&sW[(ct * 16 + m) * KP + ks + quad * 8];
        acc[ct] = __builtin_amdgcn_mfma_f32_16x16x32_f16(a, b, acc[ct], 0, 0, 0);
      }
    }

    // stats into persistent registers
    if constexpr (STATS) {
#pragma unroll
      for (int ct = 0; ct < 8; ct++) {
        int c = ct * 16 + m;
        float b = sB[c];
#pragma unroll
        for (int r = 0; r < 4; r++) {
          if (row0 + crow + r < NN) {
            float g = acc[ct][r] + b;
            ps[ct] += g;
            pq[ct] += g * g;
          }
        }
      }
    }
    if constexpr (REUSE) __syncthreads();  // all waves done reading sA

    // C -> LDS with bias (padded stride CP)
#pragma unroll
    for (int ct = 0; ct < 8; ct++) {
      int c = ct * 16 + m;
      float b = sB[c];
#pragma unroll
      for (int r = 0; r < 4; r++) sC[(crow + r) * CP + c] = (_Float16)(acc[ct][r] + b);
    }
    __syncthreads();

    // coalesced store
    {
      int r = tid >> 2, col0 = (tid & 3) * 32;
      int gr = row0 + r;
      if (gr < NN) {
        const uint4* src = (const uint4*)&sC[r * CP + col0];
        uint4* dst = (uint4*)(Gout + (long)gr * 128 + col0);
#pragma unroll
        for (int ch = 0; ch < 4; ch++) dst[ch] = src[ch];
      }
    }
  }

  // flush stats: shfl over half-waves -> LDS -> one staggered global atomic/col
  if constexpr (STATS) {
#pragma unroll
    for (int ct = 0; ct < 8; ct++) {
      float s = ps[ct], q = pq[ct];
      s += __shfl_xor(s, 16);
      q += __shfl_xor(q, 16);
      s += __shfl_xor(s, 32);
      q += __shfl_xor(q, 32);
      if (quad == 0) {
        atomicAdd(&ssum[ct * 16 + m], s);
        atomicAdd(&ssq[ct * 16 + m], q);
      }
    }
    __syncthreads();
    if (tid < 128) {
      int c = (tid + blockIdx.x * 8) & 127;  // stagger column order across blocks
      atomicAdd(&stG[c], ssum[c]);
      atomicAdd(&stG[128 + c], ssq[c]);
    }
  }
}

// ---------------- pool: per-graph segmented reduction (batch sorted, no atomics) ----

__global__ __launch_bounds__(128) void k_pool2(const ushort* __restrict__ G,
                                               const float* __restrict__ st,
                                               const float* __restrict__ gamma,
                                               const float* __restrict__ beta,
                                               const int* __restrict__ batch,
                                               float* __restrict__ hp) {
  __shared__ int sse[2];
  int g = blockIdx.x;
  int c = threadIdx.x;
  if (c < 2) {
    int key = g + c;
    int lo = 0, hi = NN;
    while (lo < hi) {
      int mid = (lo + hi) >> 1;
      if (batch[mid] < key) lo = mid + 1;
      else hi = mid;
    }
    sse[c] = lo;
  }
  __syncthreads();
  int s = sse[0], e = sse[1];
  float m = st[c] * (1.f / NN);
  float v = st[128 + c] * (1.f / NN) - m * m;
  float sc = rsqrtf(v + 1e-5f) * gamma[c];
  float tc = beta[c] - m * sc;
  float acc = 0.f;
  for (int n = s; n < e; n++) acc += fmaxf(h2f(G[(long)n * 128 + c]) * sc + tc, 0.f);
  hp[(long)g * 128 + c] = acc;
}

// ---------------- head column stats (fp32) ----------------

__global__ void k_colstats(const float* __restrict__ X, int rows, float* __restrict__ st) {
  int c = threadIdx.x;
  int C = blockDim.x;
  float s = 0.f, q = 0.f;
  for (int r = blockIdx.x; r < rows; r += gridDim.x) {
    float v = X[(long)r * C + c];
    s += v;
    q += v * v;
  }
  atomicAdd(&st[c], s);
  atomicAdd(&st[C + c], q);
}

// ---------------- MLP head ----------------

template <int KIN, int MODE>
__global__ __launch_bounds__(256) void k_fc(const float* __restrict__ X,
                                            const float* __restrict__ W,
                                            const float* __restrict__ b,
                                            const float* __restrict__ st,
                                            const float* __restrict__ gamma,
                                            const float* __restrict__ beta,
                                            float* __restrict__ Y) {
  __shared__ float sx[KIN];
  int g = blockIdx.x;
  int c = threadIdx.x;
  for (int k = c; k < KIN; k += 256) {
    float v = X[(long)g * KIN + k];
    if constexpr (MODE == 2) {
      float m = st[k] * (1.f / GGv);
      float var = st[KIN + k] * (1.f / GGv) - m * m;
      v = fmaxf((v - m) * rsqrtf(var + 1e-5f) * gamma[k] + beta[k], 0.f);
    }
    sx[k] = v;
  }
  __syncthreads();
  float acc = b[c];
#pragma unroll 8
  for (int k = 0; k < KIN; k++) acc += sx[k] * W[(long)k * 256 + c];
  Y[(long)g * 256 + c] = (MODE == 0) ? fmaxf(acc, 0.f) : acc;
}

__global__ __launch_bounds__(256) void k_out(const float* __restrict__ X,
                                             const float* __restrict__ st,
                                             const float* __restrict__ gamma,
                                             const float* __restrict__ beta,
                                             const float* __restrict__ Wout,
                                             const float* __restrict__ bout,
                                             float* __restrict__ out) {
  int g = blockIdx.x * 4 + (threadIdx.x >> 6);
  int l = threadIdx.x & 63;
  float a0 = 0.f, a1 = 0.f;
  for (int k = l; k < LBv; k += 64) {
    float z = X[(long)g * LBv + k];
    float m = st[k] * (1.f / GGv);
    float var = st[LBv + k] * (1.f / GGv) - m * m;
    float x = fmaxf((z - m) * rsqrtf(var + 1e-5f) * gamma[k] + beta[k], 0.f);
    a0 += x * Wout[2 * k];
    a1 += x * Wout[2 * k + 1];
  }
  for (int off = 32; off > 0; off >>= 1) {
    a0 += __shfl_down(a0, off);
    a1 += __shfl_down(a1, off);
  }
  if (l == 0) {
    out[2 * g] = a0 + bout[0];
    out[2 * g + 1] = a1 + bout[1];
  }
}

// ---------------- launch ----------------

extern "C" void kernel_launch(void* const* d_in, const int* in_sizes, int n_in,
                              void* d_out, int out_size, void* d_ws, size_t ws_size,
                              hipStream_t stream) {
  const float* x = (const float*)d_in[0];
  const int* ei = (const int*)d_in[1];
  const int* batch = (const int*)d_in[2];
  const float* W0 = (const float*)d_in[4];
  const float* b0 = (const float*)d_in[5];
  const float* Wg = (const float*)d_in[6];
  const float* bg = (const float*)d_in[7];
  const float* gamma_g = (const float*)d_in[8];
  const float* beta_g = (const float*)d_in[9];
  const float* Wl0 = (const float*)d_in[10];
  const float* bl0 = (const float*)d_in[11];
  const float* Wl = (const float*)d_in[12];
  const float* bl = (const float*)d_in[13];
  const float* gamma_l = (const float*)d_in[14];
  const float* beta_l = (const float*)d_in[15];
  const float* Wout = (const float*)d_in[16];
  const float* bout = (const float*)d_in[17];
  float* out = (float*)d_out;

  char* w = (char*)d_ws;
  auto alloc = [&](size_t bytes) {
    void* p = (void*)w;
    w += (bytes + 255) & ~(size_t)255;
    return p;
  };
  int* bcnt = (int*)alloc((size_t)NB * 4);
  float* stAll = (float*)alloc((size_t)(4 * 256 + 2 * 512) * 4);
  size_t zspan = (char*)w - (char*)bcnt;
  uint* bkt = (uint*)alloc((size_t)NB * BCAP * 4);
  int* bbase = (int*)alloc((size_t)NB * 4);
  int* offs = (int*)alloc((size_t)(NN + 1) * 4);
  int* col = (int*)alloc((size_t)EE * 4);
  float* dinv = (float*)alloc((size_t)NN * 4);
  ushort* u = (ushort*)alloc((size_t)NN * DINv * 2);
  ushort* V = (ushort*)alloc((size_t)NN * GBv * 2);
  ushort* g = (ushort*)alloc((size_t)NN * GBv * 2);
  ushort* Wt0 = (ushort*)alloc((size_t)DINv * GBv * 2);
  ushort* Wtg = (ushort*)alloc((size_t)GDv * GBv * GBv * 2);
  float* hp = (float*)alloc((size_t)GGv * GBv * 4);
  float* m1 = (float*)alloc((size_t)GGv * LBv * 4);
  float* m2 = (float*)alloc((size_t)GGv * LBv * 4);

  float* stg = stAll;
  float* sth0 = stAll + 4 * 256;
  float* sth1 = sth0 + 512;

  hipMemsetAsync(bcnt, 0, zspan, stream);

  k_bucket<<<NBT, 256, 0, stream>>>(ei, bcnt, bkt);
  k_bscan<<<1, 256, 0, stream>>>(bcnt, bbase, offs);
  k_csr<<<NB, 256, 0, stream>>>(bkt, bcnt, bbase, offs, dinv, col);
  k_convW<<<(DINv * GBv + GDv * GBv * GBv + 255) / 256, 256, 0, stream>>>(W0, Wg, Wt0, Wtg);
  k_uprep<<<(NN * 16 + 255) / 256, 256, 0, stream>>>(x, dinv, u);

  const int AGG = NN / 16;  // 3125
  const int MMG = 512;      // persistent-W grid-stride blocks

  // layer 0
  k_agg<64, 0><<<AGG, 256, 0, stream>>>(u, col, offs, dinv, nullptr, nullptr, nullptr, V);
  k_mm<64, false><<<MMG, 256, 0, stream>>>(V, Wt0, b0, nullptr, g);

  // layer 1 (relu fold)
  k_agg<128, 1><<<AGG, 256, 0, stream>>>(g, col, offs, dinv, nullptr, nullptr, nullptr, V);
  k_mm<128, true><<<MMG, 256, 0, stream>>>(V, Wtg, bg, stg, g);

  // layers 2..4 (BN+relu fold)
  for (int i = 1; i < GDv; i++) {
    k_agg<128, 2><<<AGG, 256, 0, stream>>>(g, col, offs, dinv, stg + (size_t)(i - 1) * 256,
                                           gamma_g + (size_t)(i - 1) * GBv,
                                           beta_g + (size_t)(i - 1) * GBv, V);
    k_mm<128, true><<<MMG, 256, 0, stream>>>(V, Wtg + (size_t)i * GBv * GBv,
                                             bg + (size_t)i * GBv, stg + (size_t)i * 256, g);
  }

  // pool with final BN+relu fused (segmented, no atomics)
  k_pool2<<<GGv, 128, 0, stream>>>(g, stg + 3 * 256, gamma_g + 3 * GBv, beta_g + 3 * GBv,
                                   batch, hp);

  // head
  k_fc<GBv, 0><<<GGv, 256, 0, stream>>>(hp, Wl0, bl0, nullptr, nullptr, nullptr, m1);
  k_fc<LBv, 1><<<GGv, 256, 0, stream>>>(m1, Wl, bl, nullptr, nullptr, nullptr, m2);
  k_colstats<<<256, LBv, 0, stream>>>(m2, GGv, sth0);
  k_fc<LBv, 2><<<GGv, 256, 0, stream>>>(m2, Wl + (size_t)LBv * LBv, bl + LBv, sth0,
                                        gamma_l, beta_l, m1);
  k_colstats<<<256, LBv, 0, stream>>>(m1, GGv, sth1);
  k_out<<<GGv / 4, 256, 0, stream>>>(m1, sth1, gamma_l + LBv, beta_l + LBv, Wout, bout, out);
}